// Round 16
// baseline (6409.810 us; speedup 1.0000x reference)
//
#include <hip/hip_runtime.h>

typedef int i32x4 __attribute__((ext_vector_type(4)));
typedef float f32x4 __attribute__((ext_vector_type(4)));
typedef _Float16 h16x8 __attribute__((ext_vector_type(8)));

#define NB 64
#define NT 2048
#define ND 256
#define NH 256
#define NTHR 512
#define NCONS 4
#define GRID (NCONS + 192)
#define CHUNK 32
#define NCHUNK (NT / CHUNK)   // 64

// ---- consumer LDS byte map ----
#define WHT_OFF 0         // 64 KB: Wh B-frags, frag-linear: tile*1024 + lane*16
#define HA_OFF  65536     // 4 KB  int8 hA[16 row][256 k], k XOR-swz by row
#define VA_OFF  69632     // 4 KB  int8 vA[16 row][256 k], swz
#define LDS_BYTES 73728
// producer reuses first 16 KB as fp16 x[32 t][256 k], XOR-swizzled

#define AT_LD(p)    __hip_atomic_load((p), __ATOMIC_RELAXED, __HIP_MEMORY_SCOPE_AGENT)
#define AT_ST(p, v) __hip_atomic_store((p), (v), __ATOMIC_RELAXED, __HIP_MEMORY_SCOPE_AGENT)

__device__ __forceinline__ float sigmoid_f(float x) { return 1.f / (1.f + __expf(-x)); }
__device__ __forceinline__ float tanh_f(float x)    { return 1.f - 2.f / (1.f + __expf(2.f * x)); }
__device__ __forceinline__ float h16f(unsigned short u) {
    return (float)__builtin_bit_cast(_Float16, u);
}
__device__ __forceinline__ unsigned short f2h16(float f) {
    return __builtin_bit_cast(unsigned short, (_Float16)f);
}
__device__ __forceinline__ i32x4 mfma_i8(i32x4 a, i32x4 b, i32x4 c) {
    return __builtin_amdgcn_mfma_i32_16x16x64_i8(a, b, c, 0, 0, 0);
}
__device__ __forceinline__ f32x4 mfma_f16(h16x8 a, h16x8 b, f32x4 c) {
    return __builtin_amdgcn_mfma_f32_16x16x32_f16(a, b, c, 0, 0, 0);
}
__device__ __forceinline__ int q8(float v, float s) {
    int q = __float2int_rn(v * s);
    return q > 127 ? 127 : (q < -127 ? -127 : q);
}
// pack 4 bytes held by lanes 4m..4m+3 into a dword on lane 4m (VALU DPP, no LDS)
__device__ __forceinline__ unsigned pack4_dpp(int b) {
    const int t1 = __builtin_amdgcn_mov_dpp(b, 0xB1, 0xF, 0xF, true);   // quad [1,0,3,2]
    const int p  = (b & 0xFF) | ((t1 & 0xFF) << 8);
    const int t2 = __builtin_amdgcn_mov_dpp(p, 0x4E, 0xF, 0xF, true);   // quad [2,3,0,1]
    return (unsigned)((p & 0xFFFF) | (t2 << 16));
}
// barrier draining only LDS (lgkm); global loads/stores stay in flight.
#define BAR_LDS() asm volatile("s_waitcnt lgkmcnt(0)\n\ts_barrier" ::: "memory")

// Grid 196 x 512.
//  bid < 4  : consumer — 16 batches via MFMA i8 16x16x64. Pre-activation loads
//             SOFTWARE-PIPELINED one step ahead (hidden under MFMA+barriers);
//             hA/vA state written as DPP-packed dwords (conflict-free).
//  bid >= 4 : producer — MFMA f16 x-projection (fp32 accum), dense ring.
//             Ring capped at 64 slots -> stays L2/L3-hot, producers pace consumers.
extern "C" __global__ void __launch_bounds__(NTHR)
gru_fused(const float* __restrict__ x,
          const float* __restrict__ Wz, const float* __restrict__ bz,
          const float* __restrict__ Wr, const float* __restrict__ br,
          const float* __restrict__ Wh, const float* __restrict__ bh,
          float* __restrict__ out,
          unsigned* prodflag, unsigned* consflag,
          unsigned* pre, int ring)
{
    __shared__ __align__(16) unsigned smem_u[LDS_BYTES / 4];
    char* smem = (char*)smem_u;
    const int tid = threadIdx.x;
    const int bid = blockIdx.x;
    const int rmask = ring - 1;
    const size_t SLOTDW = 3 * 64 * 128;

    if (bid >= NCONS) {
        // ------- producer (gate g, batch b): MFMA f16 x-projection -------
        const int pg = bid - NCONS;     // 0..191
        const int g  = pg >> 6;         // 0=z 1=r 2=h
        const int b  = pg & 63;
        const float* W    = (g == 0) ? Wz : (g == 1) ? Wr : Wh;
        const float* bias = (g == 0) ? bz : (g == 1) ? br : bh;
        const int w  = tid >> 6;        // wave 0..7 -> cols w*32..+31
        const int l  = tid & 63;
        const int lr = l & 15;
        const int lg = l >> 4;

        // B-frags: Wx[k][col], lane col=lr, k = kt*32 + lg*8 + j  (64 VGPRs)
        h16x8 bf[8][2];
        #pragma unroll
        for (int kt = 0; kt < 8; ++kt)
            #pragma unroll
            for (int nt = 0; nt < 2; ++nt) {
                const int col = w * 32 + nt * 16 + lr;
                h16x8 v;
                #pragma unroll
                for (int j = 0; j < 8; ++j)
                    v[j] = (_Float16)W[(kt * 32 + lg * 8 + j) * NH + col];
                bf[kt][nt] = v;
            }
        const float bv0 = bias[w * 32 + lr];
        const float bv1 = bias[w * 32 + 16 + lr];

        for (int ch = 0; ch < NCHUNK; ++ch) {
            const int lead = ch * CHUNK + CHUNK - ring;
            if (lead > 0) {
                if (tid == 0) {
                    unsigned it = 0;
                    while ((int)AT_LD(&consflag[b >> 4]) < lead) {
                        __builtin_amdgcn_s_sleep(8);
                        if (++it > (1u << 20)) break;
                    }
                }
                __syncthreads();
            }
            const int t0 = ch * CHUNK;
            {   // stage x chunk -> fp16 LDS [32 row][256 k], 16B-granule XOR swz
                const float4* xs = reinterpret_cast<const float4*>(
                    x + ((size_t)b * NT + t0) * ND);
                #pragma unroll
                for (int rep = 0; rep < 4; ++rep) {
                    const int f   = rep * NTHR + tid;   // 0..2047 float4s
                    const float4 v = xs[f];
                    const int row = f >> 6;
                    const int k8  = (f & 63) * 8;       // byte offset of 4 halfs
                    unsigned lo = (unsigned)f2h16(v.x) | ((unsigned)f2h16(v.y) << 16);
                    unsigned hi = (unsigned)f2h16(v.z) | ((unsigned)f2h16(v.w) << 16);
                    uint2 pk; pk.x = lo; pk.y = hi;
                    *reinterpret_cast<uint2*>(smem + row * 512 +
                        (k8 ^ ((row & 7) << 4))) = pk;
                }
            }
            __syncthreads();
            // GEMM: [32 t x 256 k] x [256 k x 32 cols(this wave)]
            f32x4 acc[2][2] = {{{0,0,0,0},{0,0,0,0}},{{0,0,0,0},{0,0,0,0}}};
            #pragma unroll
            for (int kt = 0; kt < 8; ++kt) {
                #pragma unroll
                for (int mt = 0; mt < 2; ++mt) {
                    const int row = mt * 16 + lr;
                    const h16x8 a = *reinterpret_cast<const h16x8*>(
                        smem + row * 512 + ((kt * 64 + lg * 16) ^ ((row & 7) << 4)));
                    acc[mt][0] = mfma_f16(a, bf[kt][0], acc[mt][0]);
                    acc[mt][1] = mfma_f16(a, bf[kt][1], acc[mt][1]);
                }
            }
            // epilogue: +bias, fp16 col-pair pack, dense ring stores
            #pragma unroll
            for (int mt = 0; mt < 2; ++mt) {
                #pragma unroll
                for (int i = 0; i < 4; ++i) {
                    const int trow = mt * 16 + lg * 4 + i;
                    const size_t sb = (size_t)((t0 + trow) & rmask) * SLOTDW
                                    + (size_t)(g * 64 + b) * 128;
                    const float v0 = acc[mt][0][i] + bv0;
                    const float v1 = acc[mt][1][i] + bv1;
                    const int h0 = (int)f2h16(v0);
                    const int h1 = (int)f2h16(v1);
                    const int p0 = __shfl_xor(h0, 1, 64);
                    const int p1 = __shfl_xor(h1, 1, 64);
                    if (!(lr & 1)) {
                        const int c0 = w * 32 + lr;        // even col
                        const int c1 = w * 32 + 16 + lr;
                        AT_ST(pre + sb + (c0 >> 1),
                              (unsigned)h0 | ((unsigned)p0 << 16));
                        AT_ST(pre + sb + (c1 >> 1),
                              (unsigned)h1 | ((unsigned)p1 << 16));
                    }
                }
            }
            asm volatile("s_waitcnt vmcnt(0)" ::: "memory");
            __syncthreads();
            if (tid == 0) AT_ST(&prodflag[g * 64 + b], (unsigned)(ch + 1));
            __syncthreads();
        }
        return;
    }

    // ---------------- consumer: 16 batches via MFMA ----------------
    const int bg = bid;              // group 0..3 -> batches bg*16..+15
    const int B0 = bg * 16;
    const int w  = tid >> 6;         // wave -> cols w*32..+31
    const int l  = tid & 63;
    const int lr = l & 15;           // A row / B,C col in tile
    const int lg = l >> 4;           // k-group / C row-group
    const int r0 = lg * 4;
    const int colN[2] = { w * 32 + lr, w * 32 + 16 + lr };
    const int cd[2]   = { colN[0] >> 1, colN[1] >> 1 };
    const int psh     = (lr & 1) * 16;   // fp16 half-select in packed dword

    // per-col scales for the 3 h-part gates
    float mxz[2] = {1e-8f, 1e-8f}, mxr[2] = {1e-8f, 1e-8f}, mxh[2] = {1e-8f, 1e-8f};
    for (int k = 0; k < 256; ++k) {
        #pragma unroll
        for (int nt = 0; nt < 2; ++nt) {
            mxz[nt] = fmaxf(mxz[nt], fabsf(Wz[(ND + k) * NH + colN[nt]]));
            mxr[nt] = fmaxf(mxr[nt], fabsf(Wr[(ND + k) * NH + colN[nt]]));
            mxh[nt] = fmaxf(mxh[nt], fabsf(Wh[(ND + k) * NH + colN[nt]]));
        }
    }
    float dqz[2], dqr[2], dqh[2];
    #pragma unroll
    for (int nt = 0; nt < 2; ++nt) {
        dqz[nt] = mxz[nt] / 16129.f;
        dqr[nt] = mxr[nt] / 16129.f;
        dqh[nt] = mxh[nt] / 16129.f;
    }
    // z,r B-frags in regs: B[k][col], lane col=lr, k=kt*64+lg*16+j
    i32x4 bzf[4], brf[4], bzf1[4], brf1[4];
    #pragma unroll
    for (int nt = 0; nt < 2; ++nt) {
        const int col = colN[nt];
        const float qz = 127.f / mxz[nt], qr = 127.f / mxr[nt];
        #pragma unroll
        for (int kt = 0; kt < 4; ++kt) {
            int dz[4], dr[4];
            #pragma unroll
            for (int d = 0; d < 4; ++d) {
                unsigned az = 0, ar = 0;
                #pragma unroll
                for (int bb = 0; bb < 4; ++bb) {
                    const int k = kt * 64 + lg * 16 + d * 4 + bb;
                    az |= ((unsigned)(q8(Wz[(ND + k) * NH + col], qz) & 255)) << (8 * bb);
                    ar |= ((unsigned)(q8(Wr[(ND + k) * NH + col], qr) & 255)) << (8 * bb);
                }
                dz[d] = (int)az; dr[d] = (int)ar;
            }
            if (nt == 0) { bzf[kt]  = (i32x4){dz[0],dz[1],dz[2],dz[3]};
                           brf[kt]  = (i32x4){dr[0],dr[1],dr[2],dr[3]}; }
            else         { bzf1[kt] = (i32x4){dz[0],dz[1],dz[2],dz[3]};
                           brf1[kt] = (i32x4){dr[0],dr[1],dr[2],dr[3]}; }
        }
    }
    // Wh B-frags -> LDS, frag-linear (tile*1024 + lane*16): conflict-free
    #pragma unroll
    for (int nt = 0; nt < 2; ++nt) {
        const int col = colN[nt];
        const float qh = 127.f / mxh[nt];
        #pragma unroll
        for (int kt = 0; kt < 4; ++kt) {
            int dh[4];
            #pragma unroll
            for (int d = 0; d < 4; ++d) {
                unsigned ah = 0;
                #pragma unroll
                for (int bb = 0; bb < 4; ++bb) {
                    const int k = kt * 64 + lg * 16 + d * 4 + bb;
                    ah |= ((unsigned)(q8(Wh[(ND + k) * NH + col], qh) & 255)) << (8 * bb);
                }
                dh[d] = (int)ah;
            }
            *(i32x4*)(smem + WHT_OFF + ((((w * 2 + nt) * 4 + kt) * 64 + l) << 4)) =
                (i32x4){dh[0], dh[1], dh[2], dh[3]};
        }
    }
    // zero hA + vA (8 KB); h_prev in regs (lane owns its C-tile elems)
    for (int i = tid; i < 2048; i += NTHR) smem_u[HA_OFF / 4 + i] = 0u;
    float hp0[4] = {0.f, 0.f, 0.f, 0.f};
    float hp1[4] = {0.f, 0.f, 0.f, 0.f};

    // wait for chunk 0 of the 48 feeding (gate, batch) producers
    if (tid < 48) {
        const int fl = (tid >> 4) * 64 + B0 + (tid & 15);
        unsigned it = 0;
        while (AT_LD(&prodflag[fl]) < 1u) {
            __builtin_amdgcn_s_sleep(8);
            if (++it > (1u << 20)) break;
        }
    }
    __syncthreads();

    // pipelined pre-activation registers (current step's values)
    unsigned pzd[2][4], prd[2][4], phd[2][4];
    auto load_zr = [&](int t) {
        const size_t sb = (size_t)(t & rmask) * SLOTDW;
        #pragma unroll
        for (int i = 0; i < 4; ++i) {
            const size_t rz = sb + (size_t)(0 * 64 + B0 + r0 + i) * 128;
            const size_t rr = sb + (size_t)(1 * 64 + B0 + r0 + i) * 128;
            pzd[0][i] = AT_LD(pre + rz + cd[0]);
            pzd[1][i] = AT_LD(pre + rz + cd[1]);
            prd[0][i] = AT_LD(pre + rr + cd[0]);
            prd[1][i] = AT_LD(pre + rr + cd[1]);
        }
    };
    auto load_h = [&](int t) {
        const size_t sb = (size_t)(t & rmask) * SLOTDW;
        #pragma unroll
        for (int i = 0; i < 4; ++i) {
            const size_t rh = sb + (size_t)(2 * 64 + B0 + r0 + i) * 128;
            phd[0][i] = AT_LD(pre + rh + cd[0]);
            phd[1][i] = AT_LD(pre + rh + cd[1]);
        }
    };
    load_zr(0);
    load_h(0);

    #pragma unroll 1
    for (int t = 0; t < NT; ++t) {
        const int tn = t + 1;
        const bool sc = (tn < NT) && ((tn & (CHUNK - 1)) != 0);

        // ---- stage A: z,r GEMMs over hA ----
        i32x4 zc0 = {0,0,0,0}, zc1 = {0,0,0,0}, rc0 = {0,0,0,0}, rc1 = {0,0,0,0};
        #pragma unroll
        for (int kt = 0; kt < 4; ++kt) {
            const i32x4 ha = *(const i32x4*)(smem + HA_OFF + lr * 256 +
                               ((kt * 64 + lg * 16) ^ ((lr & 7) << 4)));
            zc0 = mfma_i8(ha, bzf[kt],  zc0);
            zc1 = mfma_i8(ha, bzf1[kt], zc1);
            rc0 = mfma_i8(ha, brf[kt],  rc0);
            rc1 = mfma_i8(ha, brf1[kt], rc1);
        }
        // epilogue A: gates (consume pzd/prd), v = r*h_prev -> packed dwords
        float zz0[4], zz1[4];
        #pragma unroll
        for (int i = 0; i < 4; ++i) {
            const int row = r0 + i;
            const float z0 = sigmoid_f((float)zc0[i] * dqz[0]
                             + h16f((unsigned short)(pzd[0][i] >> psh)));
            const float rg0 = sigmoid_f((float)rc0[i] * dqr[0]
                             + h16f((unsigned short)(prd[0][i] >> psh)));
            const float z1 = sigmoid_f((float)zc1[i] * dqz[1]
                             + h16f((unsigned short)(pzd[1][i] >> psh)));
            const float rg1 = sigmoid_f((float)rc1[i] * dqr[1]
                             + h16f((unsigned short)(prd[1][i] >> psh)));
            zz0[i] = z0; zz1[i] = z1;
            const int v0 = __float2int_rn(rg0 * hp0[i] * 127.f) & 255;
            const int v1 = __float2int_rn(rg1 * hp1[i] * 127.f) & 255;
            const unsigned pk0 = pack4_dpp(v0);
            const unsigned pk1 = pack4_dpp(v1);
            if (!(l & 3)) {
                const int c0 = w * 32 + (lr & ~3);
                const int c1 = c0 + 16;
                *(unsigned*)(smem + VA_OFF + row * 256 + (c0 ^ ((row & 7) << 4))) = pk0;
                *(unsigned*)(smem + VA_OFF + row * 256 + (c1 ^ ((row & 7) << 4))) = pk1;
            }
        }
        if (sc) load_zr(tn);   // prefetch next step's z,r pre (hidden: ~1 step)
        BAR_LDS();   // vA complete

        // ---- stage B: h_hat GEMM over vA (Wh frags from LDS) ----
        i32x4 hc0 = {0,0,0,0}, hc1 = {0,0,0,0};
        #pragma unroll
        for (int kt = 0; kt < 4; ++kt) {
            const i32x4 va = *(const i32x4*)(smem + VA_OFF + lr * 256 +
                               ((kt * 64 + lg * 16) ^ ((lr & 7) << 4)));
            const i32x4 wh0 = *(const i32x4*)(smem + WHT_OFF +
                               ((((w * 2 + 0) * 4 + kt) * 64 + l) << 4));
            const i32x4 wh1 = *(const i32x4*)(smem + WHT_OFF +
                               ((((w * 2 + 1) * 4 + kt) * 64 + l) << 4));
            hc0 = mfma_i8(va, wh0, hc0);
            hc1 = mfma_i8(va, wh1, hc1);
        }
        // epilogue B: tanh (consume phd), blend, store out, update state
        #pragma unroll
        for (int i = 0; i < 4; ++i) {
            const int row = r0 + i;
            const float hh0 = tanh_f((float)hc0[i] * dqh[0]
                              + h16f((unsigned short)(phd[0][i] >> psh)));
            const float hh1 = tanh_f((float)hc1[i] * dqh[1]
                              + h16f((unsigned short)(phd[1][i] >> psh)));
            const float hn0 = hp0[i] + zz0[i] * (hh0 - hp0[i]);
            const float hn1 = hp1[i] + zz1[i] * (hh1 - hp1[i]);
            hp0[i] = hn0; hp1[i] = hn1;
            out[((size_t)(B0 + row) * NT + t) * NH + colN[0]] = hn0;
            out[((size_t)(B0 + row) * NT + t) * NH + colN[1]] = hn1;
            const int b0 = __float2int_rn(hn0 * 127.f) & 255;
            const int b1 = __float2int_rn(hn1 * 127.f) & 255;
            const unsigned pk0 = pack4_dpp(b0);
            const unsigned pk1 = pack4_dpp(b1);
            if (!(l & 3)) {
                const int c0 = w * 32 + (lr & ~3);
                const int c1 = c0 + 16;
                *(unsigned*)(smem + HA_OFF + row * 256 + (c0 ^ ((row & 7) << 4))) = pk0;
                *(unsigned*)(smem + HA_OFF + row * 256 + (c1 ^ ((row & 7) << 4))) = pk1;
            }
        }
        if (sc) load_h(tn);    // prefetch next step's h-gate pre (hidden: ~1 step)
        BAR_LDS();   // hA = h_t everywhere

        if (!sc && tn < NT) {  // chunk boundary: publish + poll + synchronous load
            if (tid == 0) AT_ST(&consflag[bg], (unsigned)tn);
            const unsigned need = (unsigned)((tn >> 5) + 1);
            if (tid < 48) {
                const int fl = (tid >> 4) * 64 + B0 + (tid & 15);
                unsigned it = 0;
                while (AT_LD(&prodflag[fl]) < need) {
                    __builtin_amdgcn_s_sleep(8);
                    if (++it > (1u << 20)) break;
                }
            }
            __syncthreads();
            load_zr(tn);
            load_h(tn);
        }
    }
}

extern "C" void kernel_launch(void* const* d_in, const int* in_sizes, int n_in,
                              void* d_out, int out_size, void* d_ws, size_t ws_size,
                              hipStream_t stream) {
    const float* x  = (const float*)d_in[0];
    const float* Wz = (const float*)d_in[1];
    const float* bz = (const float*)d_in[2];
    const float* Wr = (const float*)d_in[3];
    const float* br = (const float*)d_in[4];
    const float* Wh = (const float*)d_in[5];
    const float* bh = (const float*)d_in[6];
    float* outp = (float*)d_out;

    // ring: per-slot bytes = 3*64*128*4 = 98304. Cap at 64 slots (6 MB) so the
    // rolling window stays L2/L3-hot and producers pace the consumers.
    const size_t base = 4096;
    int ring = 32;
    for (int r = 64; r >= 32; r >>= 1) {
        const size_t need = base + (size_t)r * 98304;
        if (need <= ws_size) { ring = r; break; }
    }
    char* w = (char*)d_ws;
    unsigned* prodflag = (unsigned*)w;              // [3][64]
    unsigned* consflag = (unsigned*)(w + 1024);     // [4]
    unsigned* pre = (unsigned*)(w + base);          // [ring][3][64][128] dw

    hipMemsetAsync(w, 0, 4096, stream);  // flags must start at 0 each launch
    gru_fused<<<GRID, NTHR, 0, stream>>>(x, Wz, bz, Wr, br, Wh, bh, outp,
                                         prodflag, consflag, pre, ring);
}

// Round 17
// 2589.643 us; speedup vs baseline: 2.4752x; 2.4752x over previous
//
#include <hip/hip_runtime.h>

typedef _Float16 half2_t __attribute__((ext_vector_type(2)));

#define NB 64
#define NT 2048
#define ND 256
#define NH 256
#define NTHR 256
#define CHUNK 32
#define NCHUNK (NT / CHUNK)   // 64

// LDS (dword units). Producer: x-stage [32 t][132]. Consumer: hq bytes 0..255
// (dw 0..63), vq bytes 256..511 (dw 64..127); read as BROADCAST b128 (uniform
// address across the wave), published as DPP-packed dwords (conflict-free).
#define XT_STRIDE 132
#define LDS_DW (32 * XT_STRIDE + 16)
#define VQ_BYTE 256

__device__ __forceinline__ float sigmoid_f(float x) { return 1.f / (1.f + __expf(-x)); }
__device__ __forceinline__ float tanh_f(float x)    { return 1.f - 2.f / (1.f + __expf(2.f * x)); }
__device__ __forceinline__ half2_t mkh2(float a, float b) {
    half2_t r; r.x = (_Float16)a; r.y = (_Float16)b; return r;
}
__device__ __forceinline__ half2_t u2h2(unsigned u) { return __builtin_bit_cast(half2_t, u); }
__device__ __forceinline__ float h2get(unsigned u, int idx) {
    half2_t h = u2h2(u);
    return idx ? (float)h.y : (float)h.x;
}
__device__ __forceinline__ int dot4i8(unsigned a, unsigned b, int c) {
#if __has_builtin(__builtin_amdgcn_sdot4)
    return __builtin_amdgcn_sdot4((int)a, (int)b, c, false);
#else
    int d;
    asm("v_dot4_i32_i8 %0, %1, %2, %3" : "=v"(d) : "v"(a), "v"(b), "v"(c));
    return d;
#endif
}
// pack 4 bytes held by lanes 4m..4m+3 into a dword on lane 4m (VALU DPP, no LDS)
__device__ __forceinline__ unsigned pack4_dpp(int b) {
    const int t1 = __builtin_amdgcn_mov_dpp(b, 0xB1, 0xF, 0xF, true);   // quad [1,0,3,2]
    const int p  = (b & 0xFF) | ((t1 & 0xFF) << 8);
    const int t2 = __builtin_amdgcn_mov_dpp(p, 0x4E, 0xF, 0xF, true);   // quad [2,3,0,1]
    return (unsigned)((p & 0xFFFF) | (t2 << 16));
}
// barrier draining only LDS (lgkm); global loads/stores stay in flight.
#define BAR_LDS() asm volatile("s_waitcnt lgkmcnt(0)\n\ts_barrier" ::: "memory")

// Grid 256 x 256.
//  bid <  64 : consumer — batch b, ONE column per thread, full k=256; all 3
//              gates' weights int8 in VGPRs (192 dw). h/v read as broadcast
//              b128 from LDS (conflict-free), published as DPP-packed dwords.
//              z-sigmoid deferred past the mid-step barrier (off critical path).
//  bid >= 64 : producer (gate g, batch b) — fp16 x-projections into a ring in
//              ws (64-slot cap -> L2-hot), RELAXED atomics + vmcnt drain.
extern "C" __global__ void __launch_bounds__(NTHR)
gru_fused(const float* __restrict__ x,
          const float* __restrict__ Wz, const float* __restrict__ bz,
          const float* __restrict__ Wr, const float* __restrict__ br,
          const float* __restrict__ Wh, const float* __restrict__ bh,
          float* __restrict__ out,
          unsigned* prodflag, unsigned* consflag,
          unsigned long long* preZR, unsigned* preH, int ring)
{
    __shared__ __align__(16) unsigned smem[LDS_DW];
    const int tid = threadIdx.x;
    const int bid = blockIdx.x;
    const int rmask = ring - 1;

    if (bid >= NB) {
        // ---------------- producer (identical to R11) ----------------
        const int pb = bid - NB;        // 0..191
        const int g  = pb >> 6;         // 0=z 1=r 2=h
        const int b  = pb & 63;
        const float* W    = (g == 0) ? Wz : (g == 1) ? Wr : Wh;
        const float* bias = (g == 0) ? bz : (g == 1) ? br : bh;
        const int kh = tid & 1;         // k-half (128 x-inputs)
        const int c2 = tid >> 1;        // col-pair 0..127
        const int c0 = c2 * 2, c1 = c0 + 1;

        half2_t wa[64], wb[64];         // x-part rows kh*128..+127, cols c0,c1
        #pragma unroll
        for (int j = 0; j < 64; ++j) {
            const int k = kh * 128 + 2 * j;
            wa[j] = mkh2(W[k * NH + c0], W[(k + 1) * NH + c0]);
            wb[j] = mkh2(W[k * NH + c1], W[(k + 1) * NH + c1]);
        }
        const float bv0 = bias[c0], bv1 = bias[c1];

        for (int ch = 0; ch < NCHUNK; ++ch) {
            const int lead = ch * CHUNK + CHUNK - ring;
            if (lead > 0) {
                if (tid == 0) {
                    unsigned it = 0;
                    while ((int)__hip_atomic_load(&consflag[b], __ATOMIC_RELAXED,
                                                  __HIP_MEMORY_SCOPE_AGENT) < lead) {
                        __builtin_amdgcn_s_sleep(8);
                        if (++it > (1u << 20)) break;
                    }
                }
                __syncthreads();
            }
            const int t0 = ch * CHUNK;
            {   // stage x[b][t0..t0+31][:] into LDS as half2, row stride 132 dw
                const float4* xs = reinterpret_cast<const float4*>(
                    x + (size_t)b * NT * ND + (size_t)t0 * ND);
                #pragma unroll
                for (int rep = 0; rep < 8; ++rep) {
                    const int f = rep * NTHR + tid;     // 0..2047 float4s
                    const float4 v = xs[f];
                    const int tt = f >> 6;
                    const int u2 = f & 63;
                    uint2 pk;
                    pk.x = __builtin_bit_cast(unsigned, mkh2(v.x, v.y));
                    pk.y = __builtin_bit_cast(unsigned, mkh2(v.z, v.w));
                    *reinterpret_cast<uint2*>(&smem[tt * XT_STRIDE + u2 * 2]) = pk;
                }
            }
            __syncthreads();
            #pragma unroll 1
            for (int t = 0; t < CHUNK; ++t) {
                const uint4* xr4 = reinterpret_cast<const uint4*>(
                    &smem[t * XT_STRIDE + kh * 64]);
                float a00 = 0.f, a01 = 0.f, a10 = 0.f, a11 = 0.f;
                #pragma unroll
                for (int i = 0; i < 16; ++i) {
                    const uint4 xv = xr4[i];
                    a00 = __builtin_amdgcn_fdot2(u2h2(xv.x), wa[i*4+0], a00, false);
                    a01 = __builtin_amdgcn_fdot2(u2h2(xv.y), wa[i*4+1], a01, false);
                    a00 = __builtin_amdgcn_fdot2(u2h2(xv.z), wa[i*4+2], a00, false);
                    a01 = __builtin_amdgcn_fdot2(u2h2(xv.w), wa[i*4+3], a01, false);
                    a10 = __builtin_amdgcn_fdot2(u2h2(xv.x), wb[i*4+0], a10, false);
                    a11 = __builtin_amdgcn_fdot2(u2h2(xv.y), wb[i*4+1], a11, false);
                    a10 = __builtin_amdgcn_fdot2(u2h2(xv.z), wb[i*4+2], a10, false);
                    a11 = __builtin_amdgcn_fdot2(u2h2(xv.w), wb[i*4+3], a11, false);
                }
                float a0 = a00 + a01, a1 = a10 + a11;
                a0 += __shfl_xor(a0, 1, 64);   // combine k-halves (lane pairs)
                a1 += __shfl_xor(a1, 1, 64);
                a0 += bv0; a1 += bv1;
                if (kh == 0) {
                    const unsigned pk = __builtin_bit_cast(unsigned, mkh2(a0, a1));
                    const size_t slot = (size_t)b * ring + ((t0 + t) & rmask);
                    if (g == 2) {
                        __hip_atomic_store(&preH[slot * 128 + c2], pk,
                                           __ATOMIC_RELAXED, __HIP_MEMORY_SCOPE_AGENT);
                    } else {
                        unsigned* zr32 = reinterpret_cast<unsigned*>(&preZR[slot * 128 + c2]);
                        __hip_atomic_store(&zr32[g], pk,
                                           __ATOMIC_RELAXED, __HIP_MEMORY_SCOPE_AGENT);
                    }
                }
            }
            asm volatile("s_waitcnt vmcnt(0)" ::: "memory");  // drain ring stores
            __syncthreads();
            if (tid == 0)
                __hip_atomic_store(&prodflag[b * 3 + g], (unsigned)(ch + 1),
                                   __ATOMIC_RELAXED, __HIP_MEMORY_SCOPE_AGENT);
            __syncthreads();
        }
        return;
    }

    // ---------------- consumer: recurrence for batch b ----------------
    const int b    = bid;
    const int c    = tid;          // column 0..255 (one per thread)
    const int l    = tid & 63;
    const int w    = tid >> 6;     // wave id
    const int sub  = c & 1;        // half of the packed pre col-pair

    // per-thread per-gate max |w| over the full 256-k column -> quant scales
    float mxz = 1e-8f, mxr = 1e-8f, mxh = 1e-8f;
    #pragma unroll 4
    for (int j = 0; j < 256; ++j) {
        mxz = fmaxf(mxz, fabsf(Wz[(ND + j) * NH + c]));
        mxr = fmaxf(mxr, fabsf(Wr[(ND + j) * NH + c]));
        mxh = fmaxf(mxh, fabsf(Wh[(ND + j) * NH + c]));
    }
    const float qsz = 127.0f / mxz, qsr = 127.0f / mxr, qsh = 127.0f / mxh;
    const float deqz = mxz / (127.0f * 127.0f);
    const float deqr = mxr / (127.0f * 127.0f);
    const float deqh = mxh / (127.0f * 127.0f);

    // quantize + pack: 16 uint4 per gate = 192 VGPRs
    uint4 wz4[16], wr4[16], wh4[16];
    #pragma unroll
    for (int i = 0; i < 16; ++i) {
        unsigned dz[4], dr[4], dh[4];
        #pragma unroll
        for (int d = 0; d < 4; ++d) {
            unsigned az = 0, ar = 0, ah = 0;
            #pragma unroll
            for (int j = 0; j < 4; ++j) {
                const int k = ND + (i * 4 + d) * 4 + j;
                const int qz = __float2int_rn(Wz[k * NH + c] * qsz);
                const int qr = __float2int_rn(Wr[k * NH + c] * qsr);
                const int qh = __float2int_rn(Wh[k * NH + c] * qsh);
                az |= ((unsigned)(qz & 255)) << (8 * j);
                ar |= ((unsigned)(qr & 255)) << (8 * j);
                ah |= ((unsigned)(qh & 255)) << (8 * j);
            }
            dz[d] = az; dr[d] = ar; dh[d] = ah;
        }
        wz4[i] = make_uint4(dz[0], dz[1], dz[2], dz[3]);
        wr4[i] = make_uint4(dr[0], dr[1], dr[2], dr[3]);
        wh4[i] = make_uint4(dh[0], dh[1], dh[2], dh[3]);
    }

    if (tid < 128) smem[tid] = 0u;   // zero hq (dw 0..63) + vq (dw 64..127)
    float hreg = 0.f;

    // wait for chunk 0 of all 3 gates
    if (tid < 3) {
        unsigned it = 0;
        while (__hip_atomic_load(&prodflag[b * 3 + tid], __ATOMIC_RELAXED,
                                 __HIP_MEMORY_SCOPE_AGENT) < 1u) {
            __builtin_amdgcn_s_sleep(8);
            if (++it > (1u << 20)) break;
        }
    }
    __syncthreads();

    const unsigned long long* zrb = preZR + (size_t)b * ring * 128 + (c >> 1);
    const unsigned*           hhb = preH  + (size_t)b * ring * 128 + (c >> 1);
    float* outb = out + (size_t)b * NT * NH + c;
    const uint4* hq4 = reinterpret_cast<const uint4*>(smem);        // broadcast
    const uint4* vq4 = hq4 + 16;

    unsigned long long zr_c = __hip_atomic_load(zrb, __ATOMIC_RELAXED, __HIP_MEMORY_SCOPE_AGENT);
    unsigned           hh_c = __hip_atomic_load(hhb, __ATOMIC_RELAXED, __HIP_MEMORY_SCOPE_AGENT);

    #pragma unroll 1
    for (int t = 0; t < NT; ++t) {
        const int tn = t + 1;
        const bool pf = (tn < NT) && ((tn & (CHUNK - 1)) != 0);
        unsigned long long zr_n = 0; unsigned hh_n = 0;
        if (pf) {   // prefetch next step's pre (L2-hot: ring is 64-slot capped)
            const int so = (tn & rmask) * 128;
            zr_n = __hip_atomic_load(zrb + so, __ATOMIC_RELAXED, __HIP_MEMORY_SCOPE_AGENT);
            hh_n = __hip_atomic_load(hhb + so, __ATOMIC_RELAXED, __HIP_MEMORY_SCOPE_AGENT);
        }

        // ---- stage A: z, r int8 dots over all 256 h (broadcast b128 reads) ----
        int az0 = 0, az1 = 0, az2 = 0, az3 = 0;
        int ar0 = 0, ar1 = 0, ar2 = 0, ar3 = 0;
        #pragma unroll
        for (int i = 0; i < 16; ++i) {
            const uint4 hv = hq4[i];      // uniform addr -> HW broadcast, no conflict
            az0 = dot4i8(hv.x, wz4[i].x, az0);
            az1 = dot4i8(hv.y, wz4[i].y, az1);
            az2 = dot4i8(hv.z, wz4[i].z, az2);
            az3 = dot4i8(hv.w, wz4[i].w, az3);
            ar0 = dot4i8(hv.x, wr4[i].x, ar0);
            ar1 = dot4i8(hv.y, wr4[i].y, ar1);
            ar2 = dot4i8(hv.z, wr4[i].z, ar2);
            ar3 = dot4i8(hv.w, wr4[i].w, ar3);
        }
        const float azf = (float)((az0 + az1) + (az2 + az3)) * deqz
                        + h2get((unsigned)(zr_c & 0xffffffffu), sub);  // raw z pre-act
        const float arf = (float)((ar0 + ar1) + (ar2 + ar3)) * deqr;
        // only r's sigmoid is on the critical path; z's is deferred past the barrier
        const float r = sigmoid_f(arf + h2get((unsigned)(zr_c >> 32), sub));
        const float v = r * hreg;
        {   // publish v[c] as int8, DPP-packed to one dword per 4 lanes
            const unsigned pk = pack4_dpp(__float2int_rn(v * 127.0f) & 255);
            if (!(l & 3)) smem[(VQ_BYTE >> 2) + (c >> 2)] = pk;
        }
        BAR_LDS();   // vq ready

        // ---- stage B: h_hat dot over v (broadcast b128), z-sigmoid in shadow ----
        const float z = sigmoid_f(azf);   // off the pre-barrier critical path
        int ah0 = 0, ah1 = 0, ah2 = 0, ah3 = 0;
        #pragma unroll
        for (int i = 0; i < 16; ++i) {
            const uint4 vv = vq4[i];
            ah0 = dot4i8(vv.x, wh4[i].x, ah0);
            ah1 = dot4i8(vv.y, wh4[i].y, ah1);
            ah2 = dot4i8(vv.z, wh4[i].z, ah2);
            ah3 = dot4i8(vv.w, wh4[i].w, ah3);
        }
        const float ahf = (float)((ah0 + ah1) + (ah2 + ah3)) * deqh;
        const float hhat = tanh_f(ahf + h2get(hh_c, sub));
        const float hn = hreg + z * (hhat - hreg);   // |hn| <= 1
        hreg = hn;
        outb[(size_t)t * NH] = hn;
        {   // publish h[c] as int8, DPP-packed
            const unsigned pk = pack4_dpp(__float2int_rn(hn * 127.0f) & 255);
            if (!(l & 3)) smem[c >> 2] = pk;
        }
        BAR_LDS();   // hq = h_t everywhere

        if (pf) {
            zr_c = zr_n; hh_c = hh_n;
        } else if (tn < NT) {        // chunk boundary: publish + poll + reload
            if (tid == 0)
                __hip_atomic_store(&consflag[b], (unsigned)tn,
                                   __ATOMIC_RELAXED, __HIP_MEMORY_SCOPE_AGENT);
            const unsigned need = (unsigned)((tn >> 5) + 1);
            if (tid < 3) {
                unsigned it = 0;
                while (__hip_atomic_load(&prodflag[b * 3 + tid], __ATOMIC_RELAXED,
                                         __HIP_MEMORY_SCOPE_AGENT) < need) {
                    __builtin_amdgcn_s_sleep(8);
                    if (++it > (1u << 20)) break;
                }
            }
            __syncthreads();
            const int so = (tn & rmask) * 128;
            zr_c = __hip_atomic_load(zrb + so, __ATOMIC_RELAXED, __HIP_MEMORY_SCOPE_AGENT);
            hh_c = __hip_atomic_load(hhb + so, __ATOMIC_RELAXED, __HIP_MEMORY_SCOPE_AGENT);
        }
    }
}

extern "C" void kernel_launch(void* const* d_in, const int* in_sizes, int n_in,
                              void* d_out, int out_size, void* d_ws, size_t ws_size,
                              hipStream_t stream) {
    const float* x  = (const float*)d_in[0];
    const float* Wz = (const float*)d_in[1];
    const float* bz = (const float*)d_in[2];
    const float* Wr = (const float*)d_in[3];
    const float* br = (const float*)d_in[4];
    const float* Wh = (const float*)d_in[5];
    const float* bh = (const float*)d_in[6];
    float* outp = (float*)d_out;

    // ring sizing: per ring-step bytes = NB*128*12 = 96 KiB. CAP AT 64 slots
    // (6 MB) so the rolling pre window stays L2/L3-hot.
    const size_t base = 4096;
    int ring = 32;
    for (int r = 64; r >= 32; r >>= 1) {
        const size_t need = base + (size_t)NB * r * 128 * 12;
        if (need <= ws_size) { ring = r; break; }
    }
    char* w = (char*)d_ws;
    unsigned* prodflag = (unsigned*)w;                 // [64][3]
    unsigned* consflag = (unsigned*)(w + 1024);        // [64]
    unsigned long long* preZR = (unsigned long long*)(w + base);          // [64][ring][128]
    unsigned* preH = (unsigned*)(w + base + (size_t)NB * ring * 128 * 8); // [64][ring][128]

    hipMemsetAsync(w, 0, 4096, stream);  // flags must start at 0 each launch
    gru_fused<<<256, NTHR, 0, stream>>>(x, Wz, bz, Wr, br, Wh, bh, outp,
                                        prodflag, consflag, preZR, preH, ring);
}

// Round 18
// 2058.898 us; speedup vs baseline: 3.1132x; 1.2578x over previous
//
#include <hip/hip_runtime.h>

typedef _Float16 half2_t __attribute__((ext_vector_type(2)));

#define NB 64
#define NT 2048
#define ND 256
#define NH 256
#define NTHR 256
#define CHUNK 32
#define NCHUNK (NT / CHUNK)   // 64

// LDS (dword units). Producer: x-stage [32 t][132]. Consumer: hq bytes 0..255
// (dw 0..63), vq bytes 256..511 (dw 64..127).
#define XT_STRIDE 132
#define LDS_DW (32 * XT_STRIDE + 16)
#define VQ_BYTE 256

__device__ __forceinline__ float sigmoid_f(float x) { return 1.f / (1.f + __expf(-x)); }
__device__ __forceinline__ float tanh_f(float x)    { return 1.f - 2.f / (1.f + __expf(2.f * x)); }
__device__ __forceinline__ half2_t mkh2(float a, float b) {
    half2_t r; r.x = (_Float16)a; r.y = (_Float16)b; return r;
}
__device__ __forceinline__ half2_t u2h2(unsigned u) { return __builtin_bit_cast(half2_t, u); }
__device__ __forceinline__ float h2get(unsigned u, int idx) {
    half2_t h = u2h2(u);
    return idx ? (float)h.y : (float)h.x;
}
__device__ __forceinline__ int dot4i8(int a, int b, int c) {
#if __has_builtin(__builtin_amdgcn_sdot4)
    return __builtin_amdgcn_sdot4(a, b, c, false);
#else
    int d;
    asm("v_dot4_i32_i8 %0, %1, %2, %3" : "=v"(d) : "v"(a), "v"(b), "v"(c));
    return d;
#endif
}
// barrier draining only LDS (lgkm); global loads/stores stay in flight.
#define BAR_LDS() asm volatile("s_waitcnt lgkmcnt(0)\n\ts_barrier" ::: "memory")

// Grid 256 x 256 (R11 structure — the session champion).
//  bid <  64 : consumer — batch b, ONE column per thread, full k=256; all 3
//              gates int8 in VGPRs (192 dw; 256-reg budget at 256 thr).
//              h/v exchanged via 1 cooperative ds_read_b128 + readlane->SGPR.
//              R18 deltas: ring-64 (L2-hot pre), z-sigmoid deferred past the
//              v-barrier, out-store after the h-publish.
//  bid >= 64 : producer (gate g, batch b) — fp16 x-projections into ring.
extern "C" __global__ void __launch_bounds__(NTHR)
gru_fused(const float* __restrict__ x,
          const float* __restrict__ Wz, const float* __restrict__ bz,
          const float* __restrict__ Wr, const float* __restrict__ br,
          const float* __restrict__ Wh, const float* __restrict__ bh,
          float* __restrict__ out,
          unsigned* prodflag, unsigned* consflag,
          unsigned long long* preZR, unsigned* preH, int ring)
{
    __shared__ __align__(16) unsigned smem[LDS_DW];
    const int tid = threadIdx.x;
    const int bid = blockIdx.x;
    const int rmask = ring - 1;

    if (bid >= NB) {
        // ---------------- producer (identical to R11) ----------------
        const int pb = bid - NB;        // 0..191
        const int g  = pb >> 6;         // 0=z 1=r 2=h
        const int b  = pb & 63;
        const float* W    = (g == 0) ? Wz : (g == 1) ? Wr : Wh;
        const float* bias = (g == 0) ? bz : (g == 1) ? br : bh;
        const int kh = tid & 1;         // k-half (128 x-inputs)
        const int c2 = tid >> 1;        // col-pair 0..127
        const int c0 = c2 * 2, c1 = c0 + 1;

        half2_t wa[64], wb[64];         // x-part rows kh*128..+127, cols c0,c1
        #pragma unroll
        for (int j = 0; j < 64; ++j) {
            const int k = kh * 128 + 2 * j;
            wa[j] = mkh2(W[k * NH + c0], W[(k + 1) * NH + c0]);
            wb[j] = mkh2(W[k * NH + c1], W[(k + 1) * NH + c1]);
        }
        const float bv0 = bias[c0], bv1 = bias[c1];

        for (int ch = 0; ch < NCHUNK; ++ch) {
            const int lead = ch * CHUNK + CHUNK - ring;
            if (lead > 0) {
                if (tid == 0) {
                    unsigned it = 0;
                    while ((int)__hip_atomic_load(&consflag[b], __ATOMIC_RELAXED,
                                                  __HIP_MEMORY_SCOPE_AGENT) < lead) {
                        __builtin_amdgcn_s_sleep(8);
                        if (++it > (1u << 20)) break;
                    }
                }
                __syncthreads();
            }
            const int t0 = ch * CHUNK;
            {   // stage x[b][t0..t0+31][:] into LDS as half2, row stride 132 dw
                const float4* xs = reinterpret_cast<const float4*>(
                    x + (size_t)b * NT * ND + (size_t)t0 * ND);
                #pragma unroll
                for (int rep = 0; rep < 8; ++rep) {
                    const int f = rep * NTHR + tid;     // 0..2047 float4s
                    const float4 v = xs[f];
                    const int tt = f >> 6;
                    const int u2 = f & 63;
                    uint2 pk;
                    pk.x = __builtin_bit_cast(unsigned, mkh2(v.x, v.y));
                    pk.y = __builtin_bit_cast(unsigned, mkh2(v.z, v.w));
                    *reinterpret_cast<uint2*>(&smem[tt * XT_STRIDE + u2 * 2]) = pk;
                }
            }
            __syncthreads();
            #pragma unroll 1
            for (int t = 0; t < CHUNK; ++t) {
                const uint4* xr4 = reinterpret_cast<const uint4*>(
                    &smem[t * XT_STRIDE + kh * 64]);
                float a00 = 0.f, a01 = 0.f, a10 = 0.f, a11 = 0.f;
                #pragma unroll
                for (int i = 0; i < 16; ++i) {
                    const uint4 xv = xr4[i];
                    a00 = __builtin_amdgcn_fdot2(u2h2(xv.x), wa[i*4+0], a00, false);
                    a01 = __builtin_amdgcn_fdot2(u2h2(xv.y), wa[i*4+1], a01, false);
                    a00 = __builtin_amdgcn_fdot2(u2h2(xv.z), wa[i*4+2], a00, false);
                    a01 = __builtin_amdgcn_fdot2(u2h2(xv.w), wa[i*4+3], a01, false);
                    a10 = __builtin_amdgcn_fdot2(u2h2(xv.x), wb[i*4+0], a10, false);
                    a11 = __builtin_amdgcn_fdot2(u2h2(xv.y), wb[i*4+1], a11, false);
                    a10 = __builtin_amdgcn_fdot2(u2h2(xv.z), wb[i*4+2], a10, false);
                    a11 = __builtin_amdgcn_fdot2(u2h2(xv.w), wb[i*4+3], a11, false);
                }
                float a0 = a00 + a01, a1 = a10 + a11;
                a0 += __shfl_xor(a0, 1, 64);   // combine k-halves (lane pairs)
                a1 += __shfl_xor(a1, 1, 64);
                a0 += bv0; a1 += bv1;
                if (kh == 0) {
                    const unsigned pk = __builtin_bit_cast(unsigned, mkh2(a0, a1));
                    const size_t slot = (size_t)b * ring + ((t0 + t) & rmask);
                    if (g == 2) {
                        __hip_atomic_store(&preH[slot * 128 + c2], pk,
                                           __ATOMIC_RELAXED, __HIP_MEMORY_SCOPE_AGENT);
                    } else {
                        unsigned* zr32 = reinterpret_cast<unsigned*>(&preZR[slot * 128 + c2]);
                        __hip_atomic_store(&zr32[g], pk,
                                           __ATOMIC_RELAXED, __HIP_MEMORY_SCOPE_AGENT);
                    }
                }
            }
            asm volatile("s_waitcnt vmcnt(0)" ::: "memory");  // drain ring stores
            __syncthreads();
            if (tid == 0)
                __hip_atomic_store(&prodflag[b * 3 + g], (unsigned)(ch + 1),
                                   __ATOMIC_RELAXED, __HIP_MEMORY_SCOPE_AGENT);
            __syncthreads();
        }
        return;
    }

    // ---------------- consumer: recurrence for batch b (R11 + 3 deltas) -----
    const int b    = bid;
    const int c    = tid;          // column 0..255 (one per thread)
    const int lane = tid & 63;
    const int sub  = c & 1;        // half of the packed pre col-pair

    // per-thread per-gate max |w| over the full 256-k column -> quant scales
    float mxz = 1e-8f, mxr = 1e-8f, mxh = 1e-8f;
    #pragma unroll 4
    for (int j = 0; j < 256; ++j) {
        mxz = fmaxf(mxz, fabsf(Wz[(ND + j) * NH + c]));
        mxr = fmaxf(mxr, fabsf(Wr[(ND + j) * NH + c]));
        mxh = fmaxf(mxh, fabsf(Wh[(ND + j) * NH + c]));
    }
    const float qsz = 127.0f / mxz, qsr = 127.0f / mxr, qsh = 127.0f / mxh;
    const float deqz = mxz / (127.0f * 127.0f);
    const float deqr = mxr / (127.0f * 127.0f);
    const float deqh = mxh / (127.0f * 127.0f);

    // quantize + pack: 16 uint4 per gate = 192 VGPRs
    uint4 wz4[16], wr4[16], wh4[16];
    #pragma unroll
    for (int i = 0; i < 16; ++i) {
        unsigned dz[4], dr[4], dh[4];
        #pragma unroll
        for (int d = 0; d < 4; ++d) {
            unsigned az = 0, ar = 0, ah = 0;
            #pragma unroll
            for (int j = 0; j < 4; ++j) {
                const int k = ND + (i * 4 + d) * 4 + j;
                const int qz = __float2int_rn(Wz[k * NH + c] * qsz);
                const int qr = __float2int_rn(Wr[k * NH + c] * qsr);
                const int qh = __float2int_rn(Wh[k * NH + c] * qsh);
                az |= ((unsigned)(qz & 255)) << (8 * j);
                ar |= ((unsigned)(qr & 255)) << (8 * j);
                ah |= ((unsigned)(qh & 255)) << (8 * j);
            }
            dz[d] = az; dr[d] = ar; dh[d] = ah;
        }
        wz4[i] = make_uint4(dz[0], dz[1], dz[2], dz[3]);
        wr4[i] = make_uint4(dr[0], dr[1], dr[2], dr[3]);
        wh4[i] = make_uint4(dh[0], dh[1], dh[2], dh[3]);
    }

    if (tid < 128) smem[tid] = 0u;   // zero hq + vq (h0 = 0)
    float hreg = 0.f;

    // wait for chunk 0 of all 3 gates
    if (tid < 3) {
        unsigned it = 0;
        while (__hip_atomic_load(&prodflag[b * 3 + tid], __ATOMIC_RELAXED,
                                 __HIP_MEMORY_SCOPE_AGENT) < 1u) {
            __builtin_amdgcn_s_sleep(8);
            if (++it > (1u << 20)) break;
        }
    }
    __syncthreads();

    const unsigned long long* zrb = preZR + (size_t)b * ring * 128 + (c >> 1);
    const unsigned*           hhb = preH  + (size_t)b * ring * 128 + (c >> 1);
    float* outb = out + (size_t)b * NT * NH + c;
    const uint4* hq4 = reinterpret_cast<const uint4*>(smem);
    const uint4* vq4 = reinterpret_cast<const uint4*>(
                           reinterpret_cast<const char*>(smem) + VQ_BYTE);
    char* hqb = reinterpret_cast<char*>(smem);

    unsigned long long zr_c = __hip_atomic_load(zrb, __ATOMIC_RELAXED, __HIP_MEMORY_SCOPE_AGENT);
    unsigned           hh_c = __hip_atomic_load(hhb, __ATOMIC_RELAXED, __HIP_MEMORY_SCOPE_AGENT);

    #pragma unroll 1
    for (int t = 0; t < NT; ++t) {
        const int tn = t + 1;
        const bool pf = (tn < NT) && ((tn & (CHUNK - 1)) != 0);
        unsigned long long zr_n = 0; unsigned hh_n = 0;
        if (pf) {   // prefetch next step's pre (L2-hot: ring is 64-slot capped)
            const int so = (tn & rmask) * 128;
            zr_n = __hip_atomic_load(zrb + so, __ATOMIC_RELAXED, __HIP_MEMORY_SCOPE_AGENT);
            hh_n = __hip_atomic_load(hhb + so, __ATOMIC_RELAXED, __HIP_MEMORY_SCOPE_AGENT);
        }

        // ---- stage A: z, r int8 dots (h via 1 ds_read + readlane->SGPR) ----
        const uint4 hvec = hq4[lane & 15];    // one cooperative b128 per wave
        int az0 = 0, az1 = 0, az2 = 0, az3 = 0;
        int ar0 = 0, ar1 = 0, ar2 = 0, ar3 = 0;
        #pragma unroll
        for (int i = 0; i < 16; ++i) {
            const int sx = __builtin_amdgcn_readlane((int)hvec.x, i);
            const int sy = __builtin_amdgcn_readlane((int)hvec.y, i);
            const int sz = __builtin_amdgcn_readlane((int)hvec.z, i);
            const int sw = __builtin_amdgcn_readlane((int)hvec.w, i);
            az0 = dot4i8(sx, (int)wz4[i].x, az0);
            az1 = dot4i8(sy, (int)wz4[i].y, az1);
            az2 = dot4i8(sz, (int)wz4[i].z, az2);
            az3 = dot4i8(sw, (int)wz4[i].w, az3);
            ar0 = dot4i8(sx, (int)wr4[i].x, ar0);
            ar1 = dot4i8(sy, (int)wr4[i].y, ar1);
            ar2 = dot4i8(sz, (int)wr4[i].z, ar2);
            ar3 = dot4i8(sw, (int)wr4[i].w, ar3);
        }
        // raw z pre-act; sigmoid DEFERRED past the barrier (delta 2)
        const float azf = (float)((az0 + az1) + (az2 + az3)) * deqz
                        + h2get((unsigned)(zr_c & 0xffffffffu), sub);
        const float arf = (float)((ar0 + ar1) + (ar2 + ar3)) * deqr;
        const float r = sigmoid_f(arf + h2get((unsigned)(zr_c >> 32), sub));
        const float v = r * hreg;
        ldsb_publish_v:
        hqb[VQ_BYTE + c] = (char)__float2int_rn(v * 127.0f);   // publish v[c] int8
        BAR_LDS();   // vq ready

        // ---- stage B: h_hat dot over v; z-sigmoid in the shadow ----
        const float z = sigmoid_f(azf);
        const uint4 vvec = vq4[lane & 15];
        int ah0 = 0, ah1 = 0, ah2 = 0, ah3 = 0;
        #pragma unroll
        for (int i = 0; i < 16; ++i) {
            const int sx = __builtin_amdgcn_readlane((int)vvec.x, i);
            const int sy = __builtin_amdgcn_readlane((int)vvec.y, i);
            const int sz = __builtin_amdgcn_readlane((int)vvec.z, i);
            const int sw = __builtin_amdgcn_readlane((int)vvec.w, i);
            ah0 = dot4i8(sx, (int)wh4[i].x, ah0);
            ah1 = dot4i8(sy, (int)wh4[i].y, ah1);
            ah2 = dot4i8(sz, (int)wh4[i].z, ah2);
            ah3 = dot4i8(sw, (int)wh4[i].w, ah3);
        }
        const float ahf = (float)((ah0 + ah1) + (ah2 + ah3)) * deqh;
        const float hhat = tanh_f(ahf + h2get(hh_c, sub));
        const float hn = hreg + z * (hhat - hreg);   // |hn| <= 1
        hreg = hn;
        hqb[c] = (char)__float2int_rn(hn * 127.0f);  // publish h[c] FIRST (delta 3)
        outb[(size_t)t * NH] = hn;                   // out-store off the barrier path
        BAR_LDS();   // hq = h_t everywhere

        if (pf) {
            zr_c = zr_n; hh_c = hh_n;
        } else if (tn < NT) {        // chunk boundary: publish + poll + reload
            if (tid == 0)
                __hip_atomic_store(&consflag[b], (unsigned)tn,
                                   __ATOMIC_RELAXED, __HIP_MEMORY_SCOPE_AGENT);
            const unsigned need = (unsigned)((tn >> 5) + 1);
            if (tid < 3) {
                unsigned it = 0;
                while (__hip_atomic_load(&prodflag[b * 3 + tid], __ATOMIC_RELAXED,
                                         __HIP_MEMORY_SCOPE_AGENT) < need) {
                    __builtin_amdgcn_s_sleep(8);
                    if (++it > (1u << 20)) break;
                }
            }
            __syncthreads();
            const int so = (tn & rmask) * 128;
            zr_c = __hip_atomic_load(zrb + so, __ATOMIC_RELAXED, __HIP_MEMORY_SCOPE_AGENT);
            hh_c = __hip_atomic_load(hhb + so, __ATOMIC_RELAXED, __HIP_MEMORY_SCOPE_AGENT);
        }
    }
}

extern "C" void kernel_launch(void* const* d_in, const int* in_sizes, int n_in,
                              void* d_out, int out_size, void* d_ws, size_t ws_size,
                              hipStream_t stream) {
    const float* x  = (const float*)d_in[0];
    const float* Wz = (const float*)d_in[1];
    const float* bz = (const float*)d_in[2];
    const float* Wr = (const float*)d_in[3];
    const float* br = (const float*)d_in[4];
    const float* Wh = (const float*)d_in[5];
    const float* bh = (const float*)d_in[6];
    float* outp = (float*)d_out;

    // ring sizing: per ring-step bytes = NB*128*12 = 96 KiB. CAP AT 64 slots
    // (6 MB) so the rolling pre window stays L2/L3-hot (delta 1).
    const size_t base = 4096;
    int ring = 32;
    for (int r = 64; r >= 32; r >>= 1) {
        const size_t need = base + (size_t)NB * r * 128 * 12;
        if (need <= ws_size) { ring = r; break; }
    }
    char* w = (char*)d_ws;
    unsigned* prodflag = (unsigned*)w;                 // [64][3]
    unsigned* consflag = (unsigned*)(w + 1024);        // [64]
    unsigned long long* preZR = (unsigned long long*)(w + base);          // [64][ring][128]
    unsigned* preH = (unsigned*)(w + base + (size_t)NB * ring * 128 * 8); // [64][ring][128]

    hipMemsetAsync(w, 0, 4096, stream);  // flags must start at 0 each launch
    gru_fused<<<256, NTHR, 0, stream>>>(x, Wz, bz, Wr, br, Wh, bh, outp,
                                        prodflag, consflag, preZR, preH, ring);
}

// Round 19
// 1921.266 us; speedup vs baseline: 3.3362x; 1.0716x over previous
//
#include <hip/hip_runtime.h>

typedef _Float16 half2_t __attribute__((ext_vector_type(2)));

#define NB 64
#define NT 2048
#define ND 256
#define NH 256
#define NTHR 256
#define CHUNK 32
#define NCHUNK (NT / CHUNK)   // 64

// LDS (dword units). Producer: x-stage [32 t][132]. Consumer: hq bytes 0..255
// (dw 0..63), vq bytes 256..511 (dw 64..127).
#define XT_STRIDE 132
#define LDS_DW (32 * XT_STRIDE + 16)
#define VQ_BYTE 256

__device__ __forceinline__ float sigmoid_f(float x) { return 1.f / (1.f + __expf(-x)); }
__device__ __forceinline__ float tanh_f(float x)    { return 1.f - 2.f / (1.f + __expf(2.f * x)); }
__device__ __forceinline__ half2_t mkh2(float a, float b) {
    half2_t r; r.x = (_Float16)a; r.y = (_Float16)b; return r;
}
__device__ __forceinline__ half2_t u2h2(unsigned u) { return __builtin_bit_cast(half2_t, u); }
__device__ __forceinline__ float h2get(unsigned u, int idx) {
    half2_t h = u2h2(u);
    return idx ? (float)h.y : (float)h.x;
}
__device__ __forceinline__ int dot4i8(int a, int b, int c) {
#if __has_builtin(__builtin_amdgcn_sdot4)
    return __builtin_amdgcn_sdot4(a, b, c, false);
#else
    int d;
    asm("v_dot4_i32_i8 %0, %1, %2, %3" : "=v"(d) : "v"(a), "v"(b), "v"(c));
    return d;
#endif
}
// barrier draining only LDS (lgkm); global loads/stores stay in flight.
#define BAR_LDS() asm volatile("s_waitcnt lgkmcnt(0)\n\ts_barrier" ::: "memory")

// Grid 256 x 256 (R11/R18 champion structure; R19 = consumer t-loop unroll x2).
//  bid <  64 : consumer — batch b, ONE column per thread, full k=256; all 3
//              gates int8 in VGPRs (192 dw). h/v via 1 cooperative ds_read_b128
//              + readlane->SGPR broadcast. Ring-64 (L2-hot), deferred z-sigmoid.
//  bid >= 64 : producer (gate g, batch b) — fp16 x-projections into ring.
extern "C" __global__ void __launch_bounds__(NTHR)
gru_fused(const float* __restrict__ x,
          const float* __restrict__ Wz, const float* __restrict__ bz,
          const float* __restrict__ Wr, const float* __restrict__ br,
          const float* __restrict__ Wh, const float* __restrict__ bh,
          float* __restrict__ out,
          unsigned* prodflag, unsigned* consflag,
          unsigned long long* preZR, unsigned* preH, int ring)
{
    __shared__ __align__(16) unsigned smem[LDS_DW];
    const int tid = threadIdx.x;
    const int bid = blockIdx.x;
    const int rmask = ring - 1;

    if (bid >= NB) {
        // ---------------- producer (identical to R11/R18) ----------------
        const int pb = bid - NB;        // 0..191
        const int g  = pb >> 6;         // 0=z 1=r 2=h
        const int b  = pb & 63;
        const float* W    = (g == 0) ? Wz : (g == 1) ? Wr : Wh;
        const float* bias = (g == 0) ? bz : (g == 1) ? br : bh;
        const int kh = tid & 1;         // k-half (128 x-inputs)
        const int c2 = tid >> 1;        // col-pair 0..127
        const int c0 = c2 * 2, c1 = c0 + 1;

        half2_t wa[64], wb[64];         // x-part rows kh*128..+127, cols c0,c1
        #pragma unroll
        for (int j = 0; j < 64; ++j) {
            const int k = kh * 128 + 2 * j;
            wa[j] = mkh2(W[k * NH + c0], W[(k + 1) * NH + c0]);
            wb[j] = mkh2(W[k * NH + c1], W[(k + 1) * NH + c1]);
        }
        const float bv0 = bias[c0], bv1 = bias[c1];

        for (int ch = 0; ch < NCHUNK; ++ch) {
            const int lead = ch * CHUNK + CHUNK - ring;
            if (lead > 0) {
                if (tid == 0) {
                    unsigned it = 0;
                    while ((int)__hip_atomic_load(&consflag[b], __ATOMIC_RELAXED,
                                                  __HIP_MEMORY_SCOPE_AGENT) < lead) {
                        __builtin_amdgcn_s_sleep(8);
                        if (++it > (1u << 20)) break;
                    }
                }
                __syncthreads();
            }
            const int t0 = ch * CHUNK;
            {   // stage x[b][t0..t0+31][:] into LDS as half2, row stride 132 dw
                const float4* xs = reinterpret_cast<const float4*>(
                    x + (size_t)b * NT * ND + (size_t)t0 * ND);
                #pragma unroll
                for (int rep = 0; rep < 8; ++rep) {
                    const int f = rep * NTHR + tid;     // 0..2047 float4s
                    const float4 v = xs[f];
                    const int tt = f >> 6;
                    const int u2 = f & 63;
                    uint2 pk;
                    pk.x = __builtin_bit_cast(unsigned, mkh2(v.x, v.y));
                    pk.y = __builtin_bit_cast(unsigned, mkh2(v.z, v.w));
                    *reinterpret_cast<uint2*>(&smem[tt * XT_STRIDE + u2 * 2]) = pk;
                }
            }
            __syncthreads();
            #pragma unroll 1
            for (int t = 0; t < CHUNK; ++t) {
                const uint4* xr4 = reinterpret_cast<const uint4*>(
                    &smem[t * XT_STRIDE + kh * 64]);
                float a00 = 0.f, a01 = 0.f, a10 = 0.f, a11 = 0.f;
                #pragma unroll
                for (int i = 0; i < 16; ++i) {
                    const uint4 xv = xr4[i];
                    a00 = __builtin_amdgcn_fdot2(u2h2(xv.x), wa[i*4+0], a00, false);
                    a01 = __builtin_amdgcn_fdot2(u2h2(xv.y), wa[i*4+1], a01, false);
                    a00 = __builtin_amdgcn_fdot2(u2h2(xv.z), wa[i*4+2], a00, false);
                    a01 = __builtin_amdgcn_fdot2(u2h2(xv.w), wa[i*4+3], a01, false);
                    a10 = __builtin_amdgcn_fdot2(u2h2(xv.x), wb[i*4+0], a10, false);
                    a11 = __builtin_amdgcn_fdot2(u2h2(xv.y), wb[i*4+1], a11, false);
                    a10 = __builtin_amdgcn_fdot2(u2h2(xv.z), wb[i*4+2], a10, false);
                    a11 = __builtin_amdgcn_fdot2(u2h2(xv.w), wb[i*4+3], a11, false);
                }
                float a0 = a00 + a01, a1 = a10 + a11;
                a0 += __shfl_xor(a0, 1, 64);   // combine k-halves (lane pairs)
                a1 += __shfl_xor(a1, 1, 64);
                a0 += bv0; a1 += bv1;
                if (kh == 0) {
                    const unsigned pk = __builtin_bit_cast(unsigned, mkh2(a0, a1));
                    const size_t slot = (size_t)b * ring + ((t0 + t) & rmask);
                    if (g == 2) {
                        __hip_atomic_store(&preH[slot * 128 + c2], pk,
                                           __ATOMIC_RELAXED, __HIP_MEMORY_SCOPE_AGENT);
                    } else {
                        unsigned* zr32 = reinterpret_cast<unsigned*>(&preZR[slot * 128 + c2]);
                        __hip_atomic_store(&zr32[g], pk,
                                           __ATOMIC_RELAXED, __HIP_MEMORY_SCOPE_AGENT);
                    }
                }
            }
            asm volatile("s_waitcnt vmcnt(0)" ::: "memory");  // drain ring stores
            __syncthreads();
            if (tid == 0)
                __hip_atomic_store(&prodflag[b * 3 + g], (unsigned)(ch + 1),
                                   __ATOMIC_RELAXED, __HIP_MEMORY_SCOPE_AGENT);
            __syncthreads();
        }
        return;
    }

    // ---------------- consumer: recurrence for batch b ----------------
    const int b    = bid;
    const int c    = tid;          // column 0..255 (one per thread)
    const int lane = tid & 63;
    const int sub  = c & 1;        // half of the packed pre col-pair

    // per-thread per-gate max |w| over the full 256-k column -> quant scales
    float mxz = 1e-8f, mxr = 1e-8f, mxh = 1e-8f;
    #pragma unroll 4
    for (int j = 0; j < 256; ++j) {
        mxz = fmaxf(mxz, fabsf(Wz[(ND + j) * NH + c]));
        mxr = fmaxf(mxr, fabsf(Wr[(ND + j) * NH + c]));
        mxh = fmaxf(mxh, fabsf(Wh[(ND + j) * NH + c]));
    }
    const float qsz = 127.0f / mxz, qsr = 127.0f / mxr, qsh = 127.0f / mxh;
    const float deqz = mxz / (127.0f * 127.0f);
    const float deqr = mxr / (127.0f * 127.0f);
    const float deqh = mxh / (127.0f * 127.0f);

    // quantize + pack: 16 uint4 per gate = 192 VGPRs
    uint4 wz4[16], wr4[16], wh4[16];
    #pragma unroll
    for (int i = 0; i < 16; ++i) {
        unsigned dz[4], dr[4], dh[4];
        #pragma unroll
        for (int d = 0; d < 4; ++d) {
            unsigned az = 0, ar = 0, ah = 0;
            #pragma unroll
            for (int j = 0; j < 4; ++j) {
                const int k = ND + (i * 4 + d) * 4 + j;
                const int qz = __float2int_rn(Wz[k * NH + c] * qsz);
                const int qr = __float2int_rn(Wr[k * NH + c] * qsr);
                const int qh = __float2int_rn(Wh[k * NH + c] * qsh);
                az |= ((unsigned)(qz & 255)) << (8 * j);
                ar |= ((unsigned)(qr & 255)) << (8 * j);
                ah |= ((unsigned)(qh & 255)) << (8 * j);
            }
            dz[d] = az; dr[d] = ar; dh[d] = ah;
        }
        wz4[i] = make_uint4(dz[0], dz[1], dz[2], dz[3]);
        wr4[i] = make_uint4(dr[0], dr[1], dr[2], dr[3]);
        wh4[i] = make_uint4(dh[0], dh[1], dh[2], dh[3]);
    }

    if (tid < 128) smem[tid] = 0u;   // zero hq + vq (h0 = 0)
    float hreg = 0.f;

    // wait for chunk 0 of all 3 gates
    if (tid < 3) {
        unsigned it = 0;
        while (__hip_atomic_load(&prodflag[b * 3 + tid], __ATOMIC_RELAXED,
                                 __HIP_MEMORY_SCOPE_AGENT) < 1u) {
            __builtin_amdgcn_s_sleep(8);
            if (++it > (1u << 20)) break;
        }
    }
    __syncthreads();

    const unsigned long long* zrb = preZR + (size_t)b * ring * 128 + (c >> 1);
    const unsigned*           hhb = preH  + (size_t)b * ring * 128 + (c >> 1);
    float* outb = out + (size_t)b * NT * NH + c;
    const uint4* hq4 = reinterpret_cast<const uint4*>(smem);
    const uint4* vq4 = reinterpret_cast<const uint4*>(
                           reinterpret_cast<const char*>(smem) + VQ_BYTE);
    char* hqb = reinterpret_cast<char*>(smem);

    unsigned long long zr_c = __hip_atomic_load(zrb, __ATOMIC_RELAXED, __HIP_MEMORY_SCOPE_AGENT);
    unsigned           hh_c = __hip_atomic_load(hhb, __ATOMIC_RELAXED, __HIP_MEMORY_SCOPE_AGENT);

    // one GRU step: consumes (zr_c, hh_c), updates hreg, publishes v then h.
    auto step = [&](int t) {
        // ---- stage A: z, r int8 dots (h via 1 ds_read + readlane->SGPR) ----
        const uint4 hvec = hq4[lane & 15];    // one cooperative b128 per wave
        int az0 = 0, az1 = 0, az2 = 0, az3 = 0;
        int ar0 = 0, ar1 = 0, ar2 = 0, ar3 = 0;
        #pragma unroll
        for (int i = 0; i < 16; ++i) {
            const int sx = __builtin_amdgcn_readlane((int)hvec.x, i);
            const int sy = __builtin_amdgcn_readlane((int)hvec.y, i);
            const int sz = __builtin_amdgcn_readlane((int)hvec.z, i);
            const int sw = __builtin_amdgcn_readlane((int)hvec.w, i);
            az0 = dot4i8(sx, (int)wz4[i].x, az0);
            az1 = dot4i8(sy, (int)wz4[i].y, az1);
            az2 = dot4i8(sz, (int)wz4[i].z, az2);
            az3 = dot4i8(sw, (int)wz4[i].w, az3);
            ar0 = dot4i8(sx, (int)wr4[i].x, ar0);
            ar1 = dot4i8(sy, (int)wr4[i].y, ar1);
            ar2 = dot4i8(sz, (int)wr4[i].z, ar2);
            ar3 = dot4i8(sw, (int)wr4[i].w, ar3);
        }
        // raw z pre-act; sigmoid deferred past the barrier
        const float azf = (float)((az0 + az1) + (az2 + az3)) * deqz
                        + h2get((unsigned)(zr_c & 0xffffffffu), sub);
        const float arf = (float)((ar0 + ar1) + (ar2 + ar3)) * deqr;
        const float r = sigmoid_f(arf + h2get((unsigned)(zr_c >> 32), sub));
        const float v = r * hreg;
        hqb[VQ_BYTE + c] = (char)__float2int_rn(v * 127.0f);   // publish v[c] int8
        BAR_LDS();   // vq ready

        // ---- stage B: h_hat dot over v; z-sigmoid in the shadow ----
        const float z = sigmoid_f(azf);
        const uint4 vvec = vq4[lane & 15];
        int ah0 = 0, ah1 = 0, ah2 = 0, ah3 = 0;
        #pragma unroll
        for (int i = 0; i < 16; ++i) {
            const int sx = __builtin_amdgcn_readlane((int)vvec.x, i);
            const int sy = __builtin_amdgcn_readlane((int)vvec.y, i);
            const int sz = __builtin_amdgcn_readlane((int)vvec.z, i);
            const int sw = __builtin_amdgcn_readlane((int)vvec.w, i);
            ah0 = dot4i8(sx, (int)wh4[i].x, ah0);
            ah1 = dot4i8(sy, (int)wh4[i].y, ah1);
            ah2 = dot4i8(sz, (int)wh4[i].z, ah2);
            ah3 = dot4i8(sw, (int)wh4[i].w, ah3);
        }
        const float ahf = (float)((ah0 + ah1) + (ah2 + ah3)) * deqh;
        const float hhat = tanh_f(ahf + h2get(hh_c, sub));
        const float hn = hreg + z * (hhat - hreg);   // |hn| <= 1
        hreg = hn;
        hqb[c] = (char)__float2int_rn(hn * 127.0f);  // publish h[c] first
        outb[(size_t)t * NH] = hn;                   // out-store off the barrier path
        BAR_LDS();   // hq = h_t everywhere
    };
    auto load_pre = [&](int t) {
        const int so = (t & rmask) * 128;
        zr_c = __hip_atomic_load(zrb + so, __ATOMIC_RELAXED, __HIP_MEMORY_SCOPE_AGENT);
        hh_c = __hip_atomic_load(hhb + so, __ATOMIC_RELAXED, __HIP_MEMORY_SCOPE_AGENT);
    };

    // unrolled x2: boundaries (t % 32 == 0) always land on even t
    #pragma unroll 1
    for (int t = 0; t < NT; t += 2) {
        if (t && !(t & (CHUNK - 1))) {   // chunk boundary (1 in 16 pairs)
            if (tid == 0)
                __hip_atomic_store(&consflag[b], (unsigned)t,
                                   __ATOMIC_RELAXED, __HIP_MEMORY_SCOPE_AGENT);
            const unsigned need = (unsigned)((t >> 5) + 1);
            if (tid < 3) {
                unsigned it = 0;
                while (__hip_atomic_load(&prodflag[b * 3 + tid], __ATOMIC_RELAXED,
                                         __HIP_MEMORY_SCOPE_AGENT) < need) {
                    __builtin_amdgcn_s_sleep(8);
                    if (++it > (1u << 20)) break;
                }
            }
            __syncthreads();
            load_pre(t);
        }
        // prefetch t+1's pre (never a boundary: t+1 odd) — lands under step t
        unsigned long long zr_n; unsigned hh_n;
        {
            const int so = ((t + 1) & rmask) * 128;
            zr_n = __hip_atomic_load(zrb + so, __ATOMIC_RELAXED, __HIP_MEMORY_SCOPE_AGENT);
            hh_n = __hip_atomic_load(hhb + so, __ATOMIC_RELAXED, __HIP_MEMORY_SCOPE_AGENT);
        }
        step(t);
        zr_c = zr_n; hh_c = hh_n;
        // prefetch t+2's pre if it's not a chunk boundary (else loaded post-poll)
        const int t2 = t + 2;
        const bool pf2 = (t2 < NT) && ((t2 & (CHUNK - 1)) != 0);
        unsigned long long zr_n2 = 0; unsigned hh_n2 = 0;
        if (pf2) {
            const int so = (t2 & rmask) * 128;
            zr_n2 = __hip_atomic_load(zrb + so, __ATOMIC_RELAXED, __HIP_MEMORY_SCOPE_AGENT);
            hh_n2 = __hip_atomic_load(hhb + so, __ATOMIC_RELAXED, __HIP_MEMORY_SCOPE_AGENT);
        }
        step(t + 1);
        if (pf2) { zr_c = zr_n2; hh_c = hh_n2; }
    }
}

extern "C" void kernel_launch(void* const* d_in, const int* in_sizes, int n_in,
                              void* d_out, int out_size, void* d_ws, size_t ws_size,
                              hipStream_t stream) {
    const float* x  = (const float*)d_in[0];
    const float* Wz = (const float*)d_in[1];
    const float* bz = (const float*)d_in[2];
    const float* Wr = (const float*)d_in[3];
    const float* br = (const float*)d_in[4];
    const float* Wh = (const float*)d_in[5];
    const float* bh = (const float*)d_in[6];
    float* outp = (float*)d_out;

    // ring sizing: per ring-step bytes = NB*128*12 = 96 KiB. Cap at 64 slots
    // (6 MB) so the rolling pre window stays L2/L3-hot.
    const size_t base = 4096;
    int ring = 32;
    for (int r = 64; r >= 32; r >>= 1) {
        const size_t need = base + (size_t)NB * r * 128 * 12;
        if (need <= ws_size) { ring = r; break; }
    }
    char* w = (char*)d_ws;
    unsigned* prodflag = (unsigned*)w;                 // [64][3]
    unsigned* consflag = (unsigned*)(w + 1024);        // [64]
    unsigned long long* preZR = (unsigned long long*)(w + base);          // [64][ring][128]
    unsigned* preH = (unsigned*)(w + base + (size_t)NB * ring * 128 * 8); // [64][ring][128]

    hipMemsetAsync(w, 0, 4096, stream);  // flags must start at 0 each launch
    gru_fused<<<256, NTHR, 0, stream>>>(x, Wz, bz, Wr, br, Wh, bh, outp,
                                        prodflag, consflag, preZR, preH, ring);
}

// Round 20
// 1920.317 us; speedup vs baseline: 3.3379x; 1.0005x over previous
//
#include <hip/hip_runtime.h>

typedef _Float16 half2_t __attribute__((ext_vector_type(2)));

#define NB 64
#define NT 2048
#define ND 256
#define NH 256
#define NTHR 256
#define CHUNK 32
#define NCHUNK (NT / CHUNK)   // 64

// LDS (dword units). Producer: x-stage [32 t][132]. Consumer: hq bytes 0..255
// (dw 0..63), vq bytes 256..511 (dw 64..127).
#define XT_STRIDE 132
#define LDS_DW (32 * XT_STRIDE + 16)
#define VQ_BYTE 256

__device__ __forceinline__ float sigmoid_f(float x) { return 1.f / (1.f + __expf(-x)); }
__device__ __forceinline__ float tanh_f(float x)    { return 1.f - 2.f / (1.f + __expf(2.f * x)); }
__device__ __forceinline__ half2_t mkh2(float a, float b) {
    half2_t r; r.x = (_Float16)a; r.y = (_Float16)b; return r;
}
__device__ __forceinline__ half2_t u2h2(unsigned u) { return __builtin_bit_cast(half2_t, u); }
__device__ __forceinline__ float h2get(unsigned u, int idx) {
    half2_t h = u2h2(u);
    return idx ? (float)h.y : (float)h.x;
}
__device__ __forceinline__ int dot4i8(int a, int b, int c) {
#if __has_builtin(__builtin_amdgcn_sdot4)
    return __builtin_amdgcn_sdot4(a, b, c, false);
#else
    int d;
    asm("v_dot4_i32_i8 %0, %1, %2, %3" : "=v"(d) : "v"(a), "v"(b), "v"(c));
    return d;
#endif
}
// barrier draining only LDS (lgkm); global loads/stores stay in flight.
#define BAR_LDS() asm volatile("s_waitcnt lgkmcnt(0)\n\ts_barrier" ::: "memory")

// Grid 256 x 256 (R11/R18/R19 champion lineage).
// R20: z-dots DEFERRED to stage B — stage A runs only the r-chain before the
// v-publish barrier; z's 64 dots re-derive their h operands from the hvec
// register copy (persists across the barrier) inside stage B's ds_read window.
//  bid <  64 : consumer — batch b, ONE column per thread, full k=256; all 3
//              gates int8 in VGPRs (192 dw). h/v via 1 cooperative ds_read_b128
//              + readlane->SGPR broadcast. Ring-64 (L2-hot), unroll x2.
//  bid >= 64 : producer (gate g, batch b) — fp16 x-projections into ring.
extern "C" __global__ void __launch_bounds__(NTHR)
gru_fused(const float* __restrict__ x,
          const float* __restrict__ Wz, const float* __restrict__ bz,
          const float* __restrict__ Wr, const float* __restrict__ br,
          const float* __restrict__ Wh, const float* __restrict__ bh,
          float* __restrict__ out,
          unsigned* prodflag, unsigned* consflag,
          unsigned long long* preZR, unsigned* preH, int ring)
{
    __shared__ __align__(16) unsigned smem[LDS_DW];
    const int tid = threadIdx.x;
    const int bid = blockIdx.x;
    const int rmask = ring - 1;

    if (bid >= NB) {
        // ---------------- producer (identical to R11/R18/R19) ----------------
        const int pb = bid - NB;        // 0..191
        const int g  = pb >> 6;         // 0=z 1=r 2=h
        const int b  = pb & 63;
        const float* W    = (g == 0) ? Wz : (g == 1) ? Wr : Wh;
        const float* bias = (g == 0) ? bz : (g == 1) ? br : bh;
        const int kh = tid & 1;         // k-half (128 x-inputs)
        const int c2 = tid >> 1;        // col-pair 0..127
        const int c0 = c2 * 2, c1 = c0 + 1;

        half2_t wa[64], wb[64];         // x-part rows kh*128..+127, cols c0,c1
        #pragma unroll
        for (int j = 0; j < 64; ++j) {
            const int k = kh * 128 + 2 * j;
            wa[j] = mkh2(W[k * NH + c0], W[(k + 1) * NH + c0]);
            wb[j] = mkh2(W[k * NH + c1], W[(k + 1) * NH + c1]);
        }
        const float bv0 = bias[c0], bv1 = bias[c1];

        for (int ch = 0; ch < NCHUNK; ++ch) {
            const int lead = ch * CHUNK + CHUNK - ring;
            if (lead > 0) {
                if (tid == 0) {
                    unsigned it = 0;
                    while ((int)__hip_atomic_load(&consflag[b], __ATOMIC_RELAXED,
                                                  __HIP_MEMORY_SCOPE_AGENT) < lead) {
                        __builtin_amdgcn_s_sleep(8);
                        if (++it > (1u << 20)) break;
                    }
                }
                __syncthreads();
            }
            const int t0 = ch * CHUNK;
            {   // stage x[b][t0..t0+31][:] into LDS as half2, row stride 132 dw
                const float4* xs = reinterpret_cast<const float4*>(
                    x + (size_t)b * NT * ND + (size_t)t0 * ND);
                #pragma unroll
                for (int rep = 0; rep < 8; ++rep) {
                    const int f = rep * NTHR + tid;     // 0..2047 float4s
                    const float4 v = xs[f];
                    const int tt = f >> 6;
                    const int u2 = f & 63;
                    uint2 pk;
                    pk.x = __builtin_bit_cast(unsigned, mkh2(v.x, v.y));
                    pk.y = __builtin_bit_cast(unsigned, mkh2(v.z, v.w));
                    *reinterpret_cast<uint2*>(&smem[tt * XT_STRIDE + u2 * 2]) = pk;
                }
            }
            __syncthreads();
            #pragma unroll 1
            for (int t = 0; t < CHUNK; ++t) {
                const uint4* xr4 = reinterpret_cast<const uint4*>(
                    &smem[t * XT_STRIDE + kh * 64]);
                float a00 = 0.f, a01 = 0.f, a10 = 0.f, a11 = 0.f;
                #pragma unroll
                for (int i = 0; i < 16; ++i) {
                    const uint4 xv = xr4[i];
                    a00 = __builtin_amdgcn_fdot2(u2h2(xv.x), wa[i*4+0], a00, false);
                    a01 = __builtin_amdgcn_fdot2(u2h2(xv.y), wa[i*4+1], a01, false);
                    a00 = __builtin_amdgcn_fdot2(u2h2(xv.z), wa[i*4+2], a00, false);
                    a01 = __builtin_amdgcn_fdot2(u2h2(xv.w), wa[i*4+3], a01, false);
                    a10 = __builtin_amdgcn_fdot2(u2h2(xv.x), wb[i*4+0], a10, false);
                    a11 = __builtin_amdgcn_fdot2(u2h2(xv.y), wb[i*4+1], a11, false);
                    a10 = __builtin_amdgcn_fdot2(u2h2(xv.z), wb[i*4+2], a10, false);
                    a11 = __builtin_amdgcn_fdot2(u2h2(xv.w), wb[i*4+3], a11, false);
                }
                float a0 = a00 + a01, a1 = a10 + a11;
                a0 += __shfl_xor(a0, 1, 64);   // combine k-halves (lane pairs)
                a1 += __shfl_xor(a1, 1, 64);
                a0 += bv0; a1 += bv1;
                if (kh == 0) {
                    const unsigned pk = __builtin_bit_cast(unsigned, mkh2(a0, a1));
                    const size_t slot = (size_t)b * ring + ((t0 + t) & rmask);
                    if (g == 2) {
                        __hip_atomic_store(&preH[slot * 128 + c2], pk,
                                           __ATOMIC_RELAXED, __HIP_MEMORY_SCOPE_AGENT);
                    } else {
                        unsigned* zr32 = reinterpret_cast<unsigned*>(&preZR[slot * 128 + c2]);
                        __hip_atomic_store(&zr32[g], pk,
                                           __ATOMIC_RELAXED, __HIP_MEMORY_SCOPE_AGENT);
                    }
                }
            }
            asm volatile("s_waitcnt vmcnt(0)" ::: "memory");  // drain ring stores
            __syncthreads();
            if (tid == 0)
                __hip_atomic_store(&prodflag[b * 3 + g], (unsigned)(ch + 1),
                                   __ATOMIC_RELAXED, __HIP_MEMORY_SCOPE_AGENT);
            __syncthreads();
        }
        return;
    }

    // ---------------- consumer: recurrence for batch b ----------------
    const int b    = bid;
    const int c    = tid;          // column 0..255 (one per thread)
    const int lane = tid & 63;
    const int sub  = c & 1;        // half of the packed pre col-pair

    // per-thread per-gate max |w| over the full 256-k column -> quant scales
    float mxz = 1e-8f, mxr = 1e-8f, mxh = 1e-8f;
    #pragma unroll 4
    for (int j = 0; j < 256; ++j) {
        mxz = fmaxf(mxz, fabsf(Wz[(ND + j) * NH + c]));
        mxr = fmaxf(mxr, fabsf(Wr[(ND + j) * NH + c]));
        mxh = fmaxf(mxh, fabsf(Wh[(ND + j) * NH + c]));
    }
    const float qsz = 127.0f / mxz, qsr = 127.0f / mxr, qsh = 127.0f / mxh;
    const float deqz = mxz / (127.0f * 127.0f);
    const float deqr = mxr / (127.0f * 127.0f);
    const float deqh = mxh / (127.0f * 127.0f);

    // quantize + pack: 16 uint4 per gate = 192 VGPRs
    uint4 wz4[16], wr4[16], wh4[16];
    #pragma unroll
    for (int i = 0; i < 16; ++i) {
        unsigned dz[4], dr[4], dh[4];
        #pragma unroll
        for (int d = 0; d < 4; ++d) {
            unsigned az = 0, ar = 0, ah = 0;
            #pragma unroll
            for (int j = 0; j < 4; ++j) {
                const int k = ND + (i * 4 + d) * 4 + j;
                const int qz = __float2int_rn(Wz[k * NH + c] * qsz);
                const int qr = __float2int_rn(Wr[k * NH + c] * qsr);
                const int qh = __float2int_rn(Wh[k * NH + c] * qsh);
                az |= ((unsigned)(qz & 255)) << (8 * j);
                ar |= ((unsigned)(qr & 255)) << (8 * j);
                ah |= ((unsigned)(qh & 255)) << (8 * j);
            }
            dz[d] = az; dr[d] = ar; dh[d] = ah;
        }
        wz4[i] = make_uint4(dz[0], dz[1], dz[2], dz[3]);
        wr4[i] = make_uint4(dr[0], dr[1], dr[2], dr[3]);
        wh4[i] = make_uint4(dh[0], dh[1], dh[2], dh[3]);
    }

    if (tid < 128) smem[tid] = 0u;   // zero hq + vq (h0 = 0)
    float hreg = 0.f;

    // wait for chunk 0 of all 3 gates
    if (tid < 3) {
        unsigned it = 0;
        while (__hip_atomic_load(&prodflag[b * 3 + tid], __ATOMIC_RELAXED,
                                 __HIP_MEMORY_SCOPE_AGENT) < 1u) {
            __builtin_amdgcn_s_sleep(8);
            if (++it > (1u << 20)) break;
        }
    }
    __syncthreads();

    const unsigned long long* zrb = preZR + (size_t)b * ring * 128 + (c >> 1);
    const unsigned*           hhb = preH  + (size_t)b * ring * 128 + (c >> 1);
    float* outb = out + (size_t)b * NT * NH + c;
    const uint4* hq4 = reinterpret_cast<const uint4*>(smem);
    const uint4* vq4 = reinterpret_cast<const uint4*>(
                           reinterpret_cast<const char*>(smem) + VQ_BYTE);
    char* hqb = reinterpret_cast<char*>(smem);

    unsigned long long zr_c = __hip_atomic_load(zrb, __ATOMIC_RELAXED, __HIP_MEMORY_SCOPE_AGENT);
    unsigned           hh_c = __hip_atomic_load(hhb, __ATOMIC_RELAXED, __HIP_MEMORY_SCOPE_AGENT);

    // one GRU step. R20: stage A = r-chain only -> v publish; z-dots + z-sigmoid
    // run in stage B (hvec register copy persists across the barrier).
    auto step = [&](int t) {
        // ---- stage A: r-dots only (h via 1 ds_read + readlane->SGPR) ----
        const uint4 hvec = hq4[lane & 15];    // one cooperative b128 per wave
        int ar0 = 0, ar1 = 0, ar2 = 0, ar3 = 0;
        #pragma unroll
        for (int i = 0; i < 16; ++i) {
            const int sx = __builtin_amdgcn_readlane((int)hvec.x, i);
            const int sy = __builtin_amdgcn_readlane((int)hvec.y, i);
            const int sz = __builtin_amdgcn_readlane((int)hvec.z, i);
            const int sw = __builtin_amdgcn_readlane((int)hvec.w, i);
            ar0 = dot4i8(sx, (int)wr4[i].x, ar0);
            ar1 = dot4i8(sy, (int)wr4[i].y, ar1);
            ar2 = dot4i8(sz, (int)wr4[i].z, ar2);
            ar3 = dot4i8(sw, (int)wr4[i].w, ar3);
        }
        const float arf = (float)((ar0 + ar1) + (ar2 + ar3)) * deqr;
        const float r = sigmoid_f(arf + h2get((unsigned)(zr_c >> 32), sub));
        const float v = r * hreg;
        hqb[VQ_BYTE + c] = (char)__float2int_rn(v * 127.0f);   // publish v[c] int8
        BAR_LDS();   // vq ready

        // ---- stage B: z-dots (from hvec regs) + h_hat dots over v ----
        const uint4 vvec = vq4[lane & 15];    // issued now; z-work fills latency
        int az0 = 0, az1 = 0, az2 = 0, az3 = 0;
        #pragma unroll
        for (int i = 0; i < 16; ++i) {
            const int sx = __builtin_amdgcn_readlane((int)hvec.x, i);
            const int sy = __builtin_amdgcn_readlane((int)hvec.y, i);
            const int sz = __builtin_amdgcn_readlane((int)hvec.z, i);
            const int sw = __builtin_amdgcn_readlane((int)hvec.w, i);
            az0 = dot4i8(sx, (int)wz4[i].x, az0);
            az1 = dot4i8(sy, (int)wz4[i].y, az1);
            az2 = dot4i8(sz, (int)wz4[i].z, az2);
            az3 = dot4i8(sw, (int)wz4[i].w, az3);
        }
        const float azf = (float)((az0 + az1) + (az2 + az3)) * deqz
                        + h2get((unsigned)(zr_c & 0xffffffffu), sub);
        const float z = sigmoid_f(azf);
        int ah0 = 0, ah1 = 0, ah2 = 0, ah3 = 0;
        #pragma unroll
        for (int i = 0; i < 16; ++i) {
            const int sx = __builtin_amdgcn_readlane((int)vvec.x, i);
            const int sy = __builtin_amdgcn_readlane((int)vvec.y, i);
            const int sz = __builtin_amdgcn_readlane((int)vvec.z, i);
            const int sw = __builtin_amdgcn_readlane((int)vvec.w, i);
            ah0 = dot4i8(sx, (int)wh4[i].x, ah0);
            ah1 = dot4i8(sy, (int)wh4[i].y, ah1);
            ah2 = dot4i8(sz, (int)wh4[i].z, ah2);
            ah3 = dot4i8(sw, (int)wh4[i].w, ah3);
        }
        const float ahf = (float)((ah0 + ah1) + (ah2 + ah3)) * deqh;
        const float hhat = tanh_f(ahf + h2get(hh_c, sub));
        const float hn = hreg + z * (hhat - hreg);   // |hn| <= 1
        hreg = hn;
        hqb[c] = (char)__float2int_rn(hn * 127.0f);  // publish h[c] first
        outb[(size_t)t * NH] = hn;                   // out-store off the barrier path
        BAR_LDS();   // hq = h_t everywhere
    };
    auto load_pre = [&](int t) {
        const int so = (t & rmask) * 128;
        zr_c = __hip_atomic_load(zrb + so, __ATOMIC_RELAXED, __HIP_MEMORY_SCOPE_AGENT);
        hh_c = __hip_atomic_load(hhb + so, __ATOMIC_RELAXED, __HIP_MEMORY_SCOPE_AGENT);
    };

    // unrolled x2: boundaries (t % 32 == 0) always land on even t
    #pragma unroll 1
    for (int t = 0; t < NT; t += 2) {
        if (t && !(t & (CHUNK - 1))) {   // chunk boundary (1 in 16 pairs)
            if (tid == 0)
                __hip_atomic_store(&consflag[b], (unsigned)t,
                                   __ATOMIC_RELAXED, __HIP_MEMORY_SCOPE_AGENT);
            const unsigned need = (unsigned)((t >> 5) + 1);
            if (tid < 3) {
                unsigned it = 0;
                while (__hip_atomic_load(&prodflag[b * 3 + tid], __ATOMIC_RELAXED,
                                         __HIP_MEMORY_SCOPE_AGENT) < need) {
                    __builtin_amdgcn_s_sleep(8);
                    if (++it > (1u << 20)) break;
                }
            }
            __syncthreads();
            load_pre(t);
        }
        // prefetch t+1's pre (never a boundary: t+1 odd) — lands under step t
        unsigned long long zr_n; unsigned hh_n;
        {
            const int so = ((t + 1) & rmask) * 128;
            zr_n = __hip_atomic_load(zrb + so, __ATOMIC_RELAXED, __HIP_MEMORY_SCOPE_AGENT);
            hh_n = __hip_atomic_load(hhb + so, __ATOMIC_RELAXED, __HIP_MEMORY_SCOPE_AGENT);
        }
        step(t);
        zr_c = zr_n; hh_c = hh_n;
        // prefetch t+2's pre if it's not a chunk boundary (else loaded post-poll)
        const int t2 = t + 2;
        const bool pf2 = (t2 < NT) && ((t2 & (CHUNK - 1)) != 0);
        unsigned long long zr_n2 = 0; unsigned hh_n2 = 0;
        if (pf2) {
            const int so = (t2 & rmask) * 128;
            zr_n2 = __hip_atomic_load(zrb + so, __ATOMIC_RELAXED, __HIP_MEMORY_SCOPE_AGENT);
            hh_n2 = __hip_atomic_load(hhb + so, __ATOMIC_RELAXED, __HIP_MEMORY_SCOPE_AGENT);
        }
        step(t + 1);
        if (pf2) { zr_c = zr_n2; hh_c = hh_n2; }
    }
}

extern "C" void kernel_launch(void* const* d_in, const int* in_sizes, int n_in,
                              void* d_out, int out_size, void* d_ws, size_t ws_size,
                              hipStream_t stream) {
    const float* x  = (const float*)d_in[0];
    const float* Wz = (const float*)d_in[1];
    const float* bz = (const float*)d_in[2];
    const float* Wr = (const float*)d_in[3];
    const float* br = (const float*)d_in[4];
    const float* Wh = (const float*)d_in[5];
    const float* bh = (const float*)d_in[6];
    float* outp = (float*)d_out;

    // ring sizing: per ring-step bytes = NB*128*12 = 96 KiB. Cap at 64 slots
    // (6 MB) so the rolling pre window stays L2/L3-hot.
    const size_t base = 4096;
    int ring = 32;
    for (int r = 64; r >= 32; r >>= 1) {
        const size_t need = base + (size_t)NB * r * 128 * 12;
        if (need <= ws_size) { ring = r; break; }
    }
    char* w = (char*)d_ws;
    unsigned* prodflag = (unsigned*)w;                 // [64][3]
    unsigned* consflag = (unsigned*)(w + 1024);        // [64]
    unsigned long long* preZR = (unsigned long long*)(w + base);          // [64][ring][128]
    unsigned* preH = (unsigned*)(w + base + (size_t)NB * ring * 128 * 8); // [64][ring][128]

    hipMemsetAsync(w, 0, 4096, stream);  // flags must start at 0 each launch
    gru_fused<<<256, NTHR, 0, stream>>>(x, Wz, bz, Wr, br, Wh, bh, outp,
                                        prodflag, consflag, preZR, preH, ring);
}

// Round 21
// 1899.333 us; speedup vs baseline: 3.3748x; 1.0110x over previous
//
#include <hip/hip_runtime.h>

typedef _Float16 half2_t __attribute__((ext_vector_type(2)));

#define NB 64
#define NT 2048
#define ND 256
#define NH 256
#define NTHR 256
#define CHUNK 32
#define NCHUNK (NT / CHUNK)   // 64

// LDS (dword units). Producer: x-stage [32 t][132]. Consumer: hq bytes 0..255
// (dw 0..63), vq bytes 256..511 (dw 64..127).
#define XT_STRIDE 132
#define LDS_DW (32 * XT_STRIDE + 16)
#define VQ_BYTE 256

__device__ __forceinline__ float sigmoid_f(float x) { return 1.f / (1.f + __expf(-x)); }
__device__ __forceinline__ float tanh_f(float x)    { return 1.f - 2.f / (1.f + __expf(2.f * x)); }
__device__ __forceinline__ half2_t mkh2(float a, float b) {
    half2_t r; r.x = (_Float16)a; r.y = (_Float16)b; return r;
}
__device__ __forceinline__ half2_t u2h2(unsigned u) { return __builtin_bit_cast(half2_t, u); }
__device__ __forceinline__ float h2get(unsigned u, int idx) {
    half2_t h = u2h2(u);
    return idx ? (float)h.y : (float)h.x;
}
__device__ __forceinline__ int dot4i8(int a, int b, int c) {
#if __has_builtin(__builtin_amdgcn_sdot4)
    return __builtin_amdgcn_sdot4(a, b, c, false);
#else
    int d;
    asm("v_dot4_i32_i8 %0, %1, %2, %3" : "=v"(d) : "v"(a), "v"(b), "v"(c));
    return d;
#endif
}
// barrier draining only LDS (lgkm); global loads/stores stay in flight.
#define BAR_LDS() asm volatile("s_waitcnt lgkmcnt(0)\n\ts_barrier" ::: "memory")

// Grid 256 x 256 (R11/R18/R19 champion lineage).
// R21: z-dots back in stage A (shared readlane set with r — R20's deferral cost
// 64 extra readlanes for null gain); consumer t-loop unrolled x4 with rolling
// 1-ahead pre-activation prefetch.
//  bid <  64 : consumer — batch b, ONE column per thread, full k=256; all 3
//              gates int8 in VGPRs (192 dw). h/v via 1 cooperative ds_read_b128
//              + readlane->SGPR broadcast. Ring-64 (L2-hot).
//  bid >= 64 : producer (gate g, batch b) — fp16 x-projections into ring.
extern "C" __global__ void __launch_bounds__(NTHR)
gru_fused(const float* __restrict__ x,
          const float* __restrict__ Wz, const float* __restrict__ bz,
          const float* __restrict__ Wr, const float* __restrict__ br,
          const float* __restrict__ Wh, const float* __restrict__ bh,
          float* __restrict__ out,
          unsigned* prodflag, unsigned* consflag,
          unsigned long long* preZR, unsigned* preH, int ring)
{
    __shared__ __align__(16) unsigned smem[LDS_DW];
    const int tid = threadIdx.x;
    const int bid = blockIdx.x;
    const int rmask = ring - 1;

    if (bid >= NB) {
        // ---------------- producer (identical to R11/R18/R19) ----------------
        const int pb = bid - NB;        // 0..191
        const int g  = pb >> 6;         // 0=z 1=r 2=h
        const int b  = pb & 63;
        const float* W    = (g == 0) ? Wz : (g == 1) ? Wr : Wh;
        const float* bias = (g == 0) ? bz : (g == 1) ? br : bh;
        const int kh = tid & 1;         // k-half (128 x-inputs)
        const int c2 = tid >> 1;        // col-pair 0..127
        const int c0 = c2 * 2, c1 = c0 + 1;

        half2_t wa[64], wb[64];         // x-part rows kh*128..+127, cols c0,c1
        #pragma unroll
        for (int j = 0; j < 64; ++j) {
            const int k = kh * 128 + 2 * j;
            wa[j] = mkh2(W[k * NH + c0], W[(k + 1) * NH + c0]);
            wb[j] = mkh2(W[k * NH + c1], W[(k + 1) * NH + c1]);
        }
        const float bv0 = bias[c0], bv1 = bias[c1];

        for (int ch = 0; ch < NCHUNK; ++ch) {
            const int lead = ch * CHUNK + CHUNK - ring;
            if (lead > 0) {
                if (tid == 0) {
                    unsigned it = 0;
                    while ((int)__hip_atomic_load(&consflag[b], __ATOMIC_RELAXED,
                                                  __HIP_MEMORY_SCOPE_AGENT) < lead) {
                        __builtin_amdgcn_s_sleep(8);
                        if (++it > (1u << 20)) break;
                    }
                }
                __syncthreads();
            }
            const int t0 = ch * CHUNK;
            {   // stage x[b][t0..t0+31][:] into LDS as half2, row stride 132 dw
                const float4* xs = reinterpret_cast<const float4*>(
                    x + (size_t)b * NT * ND + (size_t)t0 * ND);
                #pragma unroll
                for (int rep = 0; rep < 8; ++rep) {
                    const int f = rep * NTHR + tid;     // 0..2047 float4s
                    const float4 v = xs[f];
                    const int tt = f >> 6;
                    const int u2 = f & 63;
                    uint2 pk;
                    pk.x = __builtin_bit_cast(unsigned, mkh2(v.x, v.y));
                    pk.y = __builtin_bit_cast(unsigned, mkh2(v.z, v.w));
                    *reinterpret_cast<uint2*>(&smem[tt * XT_STRIDE + u2 * 2]) = pk;
                }
            }
            __syncthreads();
            #pragma unroll 1
            for (int t = 0; t < CHUNK; ++t) {
                const uint4* xr4 = reinterpret_cast<const uint4*>(
                    &smem[t * XT_STRIDE + kh * 64]);
                float a00 = 0.f, a01 = 0.f, a10 = 0.f, a11 = 0.f;
                #pragma unroll
                for (int i = 0; i < 16; ++i) {
                    const uint4 xv = xr4[i];
                    a00 = __builtin_amdgcn_fdot2(u2h2(xv.x), wa[i*4+0], a00, false);
                    a01 = __builtin_amdgcn_fdot2(u2h2(xv.y), wa[i*4+1], a01, false);
                    a00 = __builtin_amdgcn_fdot2(u2h2(xv.z), wa[i*4+2], a00, false);
                    a01 = __builtin_amdgcn_fdot2(u2h2(xv.w), wa[i*4+3], a01, false);
                    a10 = __builtin_amdgcn_fdot2(u2h2(xv.x), wb[i*4+0], a10, false);
                    a11 = __builtin_amdgcn_fdot2(u2h2(xv.y), wb[i*4+1], a11, false);
                    a10 = __builtin_amdgcn_fdot2(u2h2(xv.z), wb[i*4+2], a10, false);
                    a11 = __builtin_amdgcn_fdot2(u2h2(xv.w), wb[i*4+3], a11, false);
                }
                float a0 = a00 + a01, a1 = a10 + a11;
                a0 += __shfl_xor(a0, 1, 64);   // combine k-halves (lane pairs)
                a1 += __shfl_xor(a1, 1, 64);
                a0 += bv0; a1 += bv1;
                if (kh == 0) {
                    const unsigned pk = __builtin_bit_cast(unsigned, mkh2(a0, a1));
                    const size_t slot = (size_t)b * ring + ((t0 + t) & rmask);
                    if (g == 2) {
                        __hip_atomic_store(&preH[slot * 128 + c2], pk,
                                           __ATOMIC_RELAXED, __HIP_MEMORY_SCOPE_AGENT);
                    } else {
                        unsigned* zr32 = reinterpret_cast<unsigned*>(&preZR[slot * 128 + c2]);
                        __hip_atomic_store(&zr32[g], pk,
                                           __ATOMIC_RELAXED, __HIP_MEMORY_SCOPE_AGENT);
                    }
                }
            }
            asm volatile("s_waitcnt vmcnt(0)" ::: "memory");  // drain ring stores
            __syncthreads();
            if (tid == 0)
                __hip_atomic_store(&prodflag[b * 3 + g], (unsigned)(ch + 1),
                                   __ATOMIC_RELAXED, __HIP_MEMORY_SCOPE_AGENT);
            __syncthreads();
        }
        return;
    }

    // ---------------- consumer: recurrence for batch b ----------------
    const int b    = bid;
    const int c    = tid;          // column 0..255 (one per thread)
    const int lane = tid & 63;
    const int sub  = c & 1;        // half of the packed pre col-pair

    // per-thread per-gate max |w| over the full 256-k column -> quant scales
    float mxz = 1e-8f, mxr = 1e-8f, mxh = 1e-8f;
    #pragma unroll 4
    for (int j = 0; j < 256; ++j) {
        mxz = fmaxf(mxz, fabsf(Wz[(ND + j) * NH + c]));
        mxr = fmaxf(mxr, fabsf(Wr[(ND + j) * NH + c]));
        mxh = fmaxf(mxh, fabsf(Wh[(ND + j) * NH + c]));
    }
    const float qsz = 127.0f / mxz, qsr = 127.0f / mxr, qsh = 127.0f / mxh;
    const float deqz = mxz / (127.0f * 127.0f);
    const float deqr = mxr / (127.0f * 127.0f);
    const float deqh = mxh / (127.0f * 127.0f);

    // quantize + pack: 16 uint4 per gate = 192 VGPRs
    uint4 wz4[16], wr4[16], wh4[16];
    #pragma unroll
    for (int i = 0; i < 16; ++i) {
        unsigned dz[4], dr[4], dh[4];
        #pragma unroll
        for (int d = 0; d < 4; ++d) {
            unsigned az = 0, ar = 0, ah = 0;
            #pragma unroll
            for (int j = 0; j < 4; ++j) {
                const int k = ND + (i * 4 + d) * 4 + j;
                const int qz = __float2int_rn(Wz[k * NH + c] * qsz);
                const int qr = __float2int_rn(Wr[k * NH + c] * qsr);
                const int qh = __float2int_rn(Wh[k * NH + c] * qsh);
                az |= ((unsigned)(qz & 255)) << (8 * j);
                ar |= ((unsigned)(qr & 255)) << (8 * j);
                ah |= ((unsigned)(qh & 255)) << (8 * j);
            }
            dz[d] = az; dr[d] = ar; dh[d] = ah;
        }
        wz4[i] = make_uint4(dz[0], dz[1], dz[2], dz[3]);
        wr4[i] = make_uint4(dr[0], dr[1], dr[2], dr[3]);
        wh4[i] = make_uint4(dh[0], dh[1], dh[2], dh[3]);
    }

    if (tid < 128) smem[tid] = 0u;   // zero hq + vq (h0 = 0)
    float hreg = 0.f;

    // wait for chunk 0 of all 3 gates
    if (tid < 3) {
        unsigned it = 0;
        while (__hip_atomic_load(&prodflag[b * 3 + tid], __ATOMIC_RELAXED,
                                 __HIP_MEMORY_SCOPE_AGENT) < 1u) {
            __builtin_amdgcn_s_sleep(8);
            if (++it > (1u << 20)) break;
        }
    }
    __syncthreads();

    const unsigned long long* zrb = preZR + (size_t)b * ring * 128 + (c >> 1);
    const unsigned*           hhb = preH  + (size_t)b * ring * 128 + (c >> 1);
    float* outb = out + (size_t)b * NT * NH + c;
    const uint4* hq4 = reinterpret_cast<const uint4*>(smem);
    const uint4* vq4 = reinterpret_cast<const uint4*>(
                           reinterpret_cast<const char*>(smem) + VQ_BYTE);
    char* hqb = reinterpret_cast<char*>(smem);

    unsigned long long zr_c = __hip_atomic_load(zrb, __ATOMIC_RELAXED, __HIP_MEMORY_SCOPE_AGENT);
    unsigned           hh_c = __hip_atomic_load(hhb, __ATOMIC_RELAXED, __HIP_MEMORY_SCOPE_AGENT);

    // one GRU step: consumes (zr_c, hh_c), updates hreg, publishes v then h.
    // z and r dot-chains SHARE one readlane set (R19 structure).
    auto step = [&](int t) {
        // ---- stage A: z, r int8 dots (h via 1 ds_read + readlane->SGPR) ----
        const uint4 hvec = hq4[lane & 15];    // one cooperative b128 per wave
        int az0 = 0, az1 = 0, az2 = 0, az3 = 0;
        int ar0 = 0, ar1 = 0, ar2 = 0, ar3 = 0;
        #pragma unroll
        for (int i = 0; i < 16; ++i) {
            const int sx = __builtin_amdgcn_readlane((int)hvec.x, i);
            const int sy = __builtin_amdgcn_readlane((int)hvec.y, i);
            const int sz = __builtin_amdgcn_readlane((int)hvec.z, i);
            const int sw = __builtin_amdgcn_readlane((int)hvec.w, i);
            az0 = dot4i8(sx, (int)wz4[i].x, az0);
            az1 = dot4i8(sy, (int)wz4[i].y, az1);
            az2 = dot4i8(sz, (int)wz4[i].z, az2);
            az3 = dot4i8(sw, (int)wz4[i].w, az3);
            ar0 = dot4i8(sx, (int)wr4[i].x, ar0);
            ar1 = dot4i8(sy, (int)wr4[i].y, ar1);
            ar2 = dot4i8(sz, (int)wr4[i].z, ar2);
            ar3 = dot4i8(sw, (int)wr4[i].w, ar3);
        }
        // raw z pre-act; sigmoid deferred past the barrier
        const float azf = (float)((az0 + az1) + (az2 + az3)) * deqz
                        + h2get((unsigned)(zr_c & 0xffffffffu), sub);
        const float arf = (float)((ar0 + ar1) + (ar2 + ar3)) * deqr;
        const float r = sigmoid_f(arf + h2get((unsigned)(zr_c >> 32), sub));
        const float v = r * hreg;
        hqb[VQ_BYTE + c] = (char)__float2int_rn(v * 127.0f);   // publish v[c] int8
        BAR_LDS();   // vq ready

        // ---- stage B: h_hat dot over v; z-sigmoid in the shadow ----
        const float z = sigmoid_f(azf);
        const uint4 vvec = vq4[lane & 15];
        int ah0 = 0, ah1 = 0, ah2 = 0, ah3 = 0;
        #pragma unroll
        for (int i = 0; i < 16; ++i) {
            const int sx = __builtin_amdgcn_readlane((int)vvec.x, i);
            const int sy = __builtin_amdgcn_readlane((int)vvec.y, i);
            const int sz = __builtin_amdgcn_readlane((int)vvec.z, i);
            const int sw = __builtin_amdgcn_readlane((int)vvec.w, i);
            ah0 = dot4i8(sx, (int)wh4[i].x, ah0);
            ah1 = dot4i8(sy, (int)wh4[i].y, ah1);
            ah2 = dot4i8(sz, (int)wh4[i].z, ah2);
            ah3 = dot4i8(sw, (int)wh4[i].w, ah3);
        }
        const float ahf = (float)((ah0 + ah1) + (ah2 + ah3)) * deqh;
        const float hhat = tanh_f(ahf + h2get(hh_c, sub));
        const float hn = hreg + z * (hhat - hreg);   // |hn| <= 1
        hreg = hn;
        hqb[c] = (char)__float2int_rn(hn * 127.0f);  // publish h[c] first
        outb[(size_t)t * NH] = hn;                   // out-store off the barrier path
        BAR_LDS();   // hq = h_t everywhere
    };
    auto prefetch = [&](int t, unsigned long long& zr_n, unsigned& hh_n) {
        const int so = (t & rmask) * 128;
        zr_n = __hip_atomic_load(zrb + so, __ATOMIC_RELAXED, __HIP_MEMORY_SCOPE_AGENT);
        hh_n = __hip_atomic_load(hhb + so, __ATOMIC_RELAXED, __HIP_MEMORY_SCOPE_AGENT);
    };

    // unrolled x4: chunk boundaries (t % 32 == 0) always land on group heads
    #pragma unroll 1
    for (int t = 0; t < NT; t += 4) {
        if (t && !(t & (CHUNK - 1))) {   // chunk boundary (1 in 8 groups)
            if (tid == 0)
                __hip_atomic_store(&consflag[b], (unsigned)t,
                                   __ATOMIC_RELAXED, __HIP_MEMORY_SCOPE_AGENT);
            const unsigned need = (unsigned)((t >> 5) + 1);
            if (tid < 3) {
                unsigned it = 0;
                while (__hip_atomic_load(&prodflag[b * 3 + tid], __ATOMIC_RELAXED,
                                         __HIP_MEMORY_SCOPE_AGENT) < need) {
                    __builtin_amdgcn_s_sleep(8);
                    if (++it > (1u << 20)) break;
                }
            }
            __syncthreads();
            prefetch(t, zr_c, hh_c);
        }
        unsigned long long zr_n; unsigned hh_n;
        // steps t, t+1, t+2 with rolling 1-ahead prefetch (never boundaries)
        prefetch(t + 1, zr_n, hh_n);
        step(t);
        zr_c = zr_n; hh_c = hh_n;
        prefetch(t + 2, zr_n, hh_n);
        step(t + 1);
        zr_c = zr_n; hh_c = hh_n;
        prefetch(t + 3, zr_n, hh_n);
        step(t + 2);
        zr_c = zr_n; hh_c = hh_n;
        // step t+3: prefetch t+4 only if not a chunk boundary (else post-poll)
        const int t4 = t + 4;
        const bool pf4 = (t4 < NT) && ((t4 & (CHUNK - 1)) != 0);
        if (pf4) prefetch(t4, zr_n, hh_n);
        step(t + 3);
        if (pf4) { zr_c = zr_n; hh_c = hh_n; }
    }
}

extern "C" void kernel_launch(void* const* d_in, const int* in_sizes, int n_in,
                              void* d_out, int out_size, void* d_ws, size_t ws_size,
                              hipStream_t stream) {
    const float* x  = (const float*)d_in[0];
    const float* Wz = (const float*)d_in[1];
    const float* bz = (const float*)d_in[2];
    const float* Wr = (const float*)d_in[3];
    const float* br = (const float*)d_in[4];
    const float* Wh = (const float*)d_in[5];
    const float* bh = (const float*)d_in[6];
    float* outp = (float*)d_out;

    // ring sizing: per ring-step bytes = NB*128*12 = 96 KiB. Cap at 64 slots
    // (6 MB) so the rolling pre window stays L2/L3-hot.
    const size_t base = 4096;
    int ring = 32;
    for (int r = 64; r >= 32; r >>= 1) {
        const size_t need = base + (size_t)NB * r * 128 * 12;
        if (need <= ws_size) { ring = r; break; }
    }
    char* w = (char*)d_ws;
    unsigned* prodflag = (unsigned*)w;                 // [64][3]
    unsigned* consflag = (unsigned*)(w + 1024);        // [64]
    unsigned long long* preZR = (unsigned long long*)(w + base);          // [64][ring][128]
    unsigned* preH = (unsigned*)(w + base + (size_t)NB * ring * 128 * 8); // [64][ring][128]

    hipMemsetAsync(w, 0, 4096, stream);  // flags must start at 0 each launch
    gru_fused<<<256, NTHR, 0, stream>>>(x, Wz, bz, Wr, br, Wh, bh, outp,
                                        prodflag, consflag, preZR, preH, ring);
}